// Round 2
// baseline (762.027 us; speedup 1.0000x reference)
//
#include <hip/hip_runtime.h>

// ---------------------------------------------------------------------------
// VectorQuantizer: N=16384 points x K=8192 codes x D=512 fp32.
// R9: R8's 256x256 8-phase schedule (T2 swizzle + T3/T4 counted vmcnt + T5
// setprio) with the VGPR-budget fix: __launch_bounds__(512, 1).
// R8 declared (512,2) -> 128-VGPR/wave budget -> accumulator spilled to
// scratch (VGPR_Count=120, WRITE_SIZE 4->34 MB, MfmaUtil 8.6%). LDS=128KiB
// already caps residency at 1 block/CU, so (512,1) costs nothing and gives
// the 256-VGPR budget the acc[8][4] f32x4 layout needs.
// Fallback (small ws): round-1 pure-fp32 VALU kernel (known-correct).
// ---------------------------------------------------------------------------

#define N_PTS   16384
#define DIM     512
#define K_CODES 8192
#define NSPLIT  16                    // code splits (512 codes each)
#define OUT0_N  (N_PTS * DIM)
#define NELEM_F (8388608.0f)
#define MARGIN  1.5e-2f

typedef _Float16 half8 __attribute__((ext_vector_type(8)));
typedef _Float16 f16x4 __attribute__((ext_vector_type(4)));
typedef float    f32x4 __attribute__((ext_vector_type(4)));

// fast-path workspace layout (bytes) — unchanged from R7
#define SZ_A3    (16384UL * 512 * 2)               // 16.8 MB
#define SZ_B3    (8192UL * 512 * 2)                // 8.4 MB
#define OFF_A3   0UL
#define OFF_B3   (OFF_A3 + SZ_A3)
#define OFF_CN   (OFF_B3 + SZ_B3)                  // cnorm 32 KB
#define OFF_PV1  (OFF_CN + 32768UL)
#define SZ_P     (16UL * 16384 * 4)                // 1 MB each
#define OFF_PI1  (OFF_PV1 + SZ_P)
#define OFF_PV2  (OFF_PI1 + SZ_P)
#define OFF_PI2  (OFF_PV2 + SZ_P)
#define OFF_PSUM (OFF_PI2 + SZ_P)                  // psums 64 KB
#define OFF_CNT  (OFF_PSUM + 65536UL)              // counts 32 KB
#define WS_NEED  (OFF_CNT + 32768UL)

#define GLOAD_LDS16(g, l) \
    __builtin_amdgcn_global_load_lds( \
        (const __attribute__((address_space(1))) unsigned int*)(g), \
        (__attribute__((address_space(3))) unsigned int*)(l), 16, 0, 0)

// ---------------------------------------------------------------- prep (fused)
__global__ __launch_bounds__(128) void prep_all(const float* __restrict__ z_e,
                                                const float* __restrict__ cb,
                                                _Float16* __restrict__ A3,
                                                _Float16* __restrict__ B3,
                                                float* __restrict__ cnorm,
                                                unsigned int* __restrict__ counts) {
    const int b = blockIdx.x;
    const int t = threadIdx.x;
    if (b < 64) counts[b * 128 + t] = 0u;
    if (b < N_PTS) {
        const long r = b;
        const int d = t * 4;
        const float4 v = *(const float4*)(z_e + r * DIM + d);
        f16x4 h;
        h[0] = (_Float16)v.x; h[1] = (_Float16)v.y;
        h[2] = (_Float16)v.z; h[3] = (_Float16)v.w;
        *(f16x4*)(A3 + r * 512 + d) = h;
    } else {
        const long r = b - N_PTS;
        const int d = t * 4;
        const float4 v = *(const float4*)(cb + r * DIM + d);
        f16x4 h;
        h[0] = (_Float16)v.x; h[1] = (_Float16)v.y;
        h[2] = (_Float16)v.z; h[3] = (_Float16)v.w;
        *(f16x4*)(B3 + r * 512 + d) = h;
        float s = v.x * v.x + v.y * v.y + v.z * v.z + v.w * v.w;
#pragma unroll
        for (int o = 32; o > 0; o >>= 1) s += __shfl_down(s, o, 64);
        __shared__ float red[2];
        if ((t & 63) == 0) red[t >> 6] = s;
        __syncthreads();
        if (t == 0) cnorm[r] = red[0] + red[1];
    }
}

// ---------------------------------------------------------------- cnorm (fallback)
__global__ __launch_bounds__(128) void cnorm_kernel(const float* __restrict__ cb,
                                                    float* __restrict__ cnorm) {
    const int k = blockIdx.x;
    const int t = threadIdx.x;
    const float4 v = *(const float4*)(cb + (size_t)k * DIM + t * 4);
    float s = v.x * v.x + v.y * v.y + v.z * v.z + v.w * v.w;
#pragma unroll
    for (int o = 32; o > 0; o >>= 1) s += __shfl_down(s, o, 64);
    __shared__ float red[2];
    if ((t & 63) == 0) red[t >> 6] = s;
    __syncthreads();
    if (t == 0) cnorm[k] = red[0] + red[1];
}

// ---------------------------------------------------------------- top2 merge
__device__ __forceinline__ void top2_merge(float& a1, int& b1, float& a2, int& b2,
                                           const float c1, const int d1,
                                           const float c2, const int d2) {
    if (c1 < a1 || (c1 == a1 && d1 < b1)) {
        if (a1 < c2 || (a1 == c2 && b1 < d2)) { a2 = a1; b2 = b1; }
        else { a2 = c2; b2 = d2; }
        a1 = c1; b1 = d1;
    } else {
        if (c1 < a2 || (c1 == a2 && d1 < b2)) { a2 = c1; b2 = d1; }
    }
}

// ---------------------------------------------------------------- score GEMM
// 256x256 tile, BK=64, 512 threads = 8 waves (2Mx4N), each wave 128x64 via
// 8x4 of 16x16x32 f16 MFMA. LDS: 2 bufs x (A 32KB + B 32KB) = 128 KiB,
// row-major [256][64] halves with 16B-chunk XOR swizzle:
//   LDS[r][c] = G[r][c ^ (r&7)]   (stage pre-swizzles the GLOBAL source,
//   read XORs the chunk; conflict-free b128 reads, verified R4-R8).
// Staging unit = quarter tile (64 rows = 1 global_load_lds/thread).
// Phase = quadrant (4mi x 2ni) x K=64: 12 ds_read_b128 + 16 MFMA.
// Stage schedule per group g (tile t=g, reads buf g&1):
//   p1: A1,A3(g+1)  p2: B0,B1(g+1)  p3: B2,B3(g+1)  p4: A0,A2(g+2)
// vmcnt(2) once per K-tile at p4 (steady), vmcnt(0) at g==6 (drain).
__global__ __launch_bounds__(512, 1) void score_kernel(
    const _Float16* __restrict__ A3, const _Float16* __restrict__ B3,
    const float* __restrict__ cnorm,
    float* __restrict__ pv1, int* __restrict__ pi1,
    float* __restrict__ pv2, int* __restrict__ pi2) {
    __shared__ _Float16 smem[65536];    // 128 KiB

    const int tid = threadIdx.x;
    const int w   = tid >> 6;           // wave 0..7
    const int l   = tid & 63;
    const int wm  = w >> 2;             // 0..1
    const int wn  = w & 3;              // 0..3
    const int m16 = l & 15;
    const int qq  = l >> 4;
    const int x7  = l & 7;
    const int pbase  = blockIdx.x * 256;
    const int nsplit = blockIdx.y;      // 0..15

    // staging: thread -> (row tid>>3, linear chunk tid&7) of a 64-row quarter;
    // global source chunk pre-swizzled so LDS[r][c] = G[r][c^(r&7)].
    const int srow = tid >> 3;          // 0..63
    const int sc   = ((tid & 7) ^ (srow & 7)) * 8;        // halves
    const _Float16* gA = A3 + (size_t)(pbase + srow) * 512 + sc;

    // read-side bases
    const int rA = wm * 128 + m16;      // A row base (+ mi*16)
    const int rB = wn * 64  + m16;      // B row base (+ ni*16)
    const int k0 = (qq ^ x7) * 8;       // ks=0 chunk offset (halves); ks=1 -> ^32

#define STAGE_A(q, tau) \
    GLOAD_LDS16(gA + (q) * 64 * 512 + (tau) * 64, \
                &smem[(((tau) & 1) * 32768) + (q) * 4096 + w * 512])
#define STAGE_B(q, tau) \
    GLOAD_LDS16(gB + (q) * 64 * 512 + (tau) * 64, \
                &smem[(((tau) & 1) * 32768) + 16384 + (q) * 4096 + w * 512])

#define PHASE(mh, nh, STAGE_STMT, VM_STMT) do {                                 \
    half8 af[4][2]; half8 bf[2][2];                                             \
    _Pragma("unroll")                                                           \
    for (int i_ = 0; i_ < 4; ++i_) {                                            \
        const int r_ = (rA + ((mh) * 4 + i_) * 16) * 64;                        \
        af[i_][0] = *(const half8*)&smem[bufo + r_ + k0];                       \
        af[i_][1] = *(const half8*)&smem[bufo + r_ + (k0 ^ 32)];                \
    }                                                                           \
    _Pragma("unroll")                                                           \
    for (int j_ = 0; j_ < 2; ++j_) {                                            \
        const int r_ = (rB + ((nh) * 2 + j_) * 16) * 64;                        \
        bf[j_][0] = *(const half8*)&smem[bufo + 16384 + r_ + k0];               \
        bf[j_][1] = *(const half8*)&smem[bufo + 16384 + r_ + (k0 ^ 32)];        \
    }                                                                           \
    STAGE_STMT;                                                                 \
    __builtin_amdgcn_s_barrier();                                               \
    asm volatile("s_waitcnt lgkmcnt(0)" ::: "memory");                          \
    __builtin_amdgcn_sched_barrier(0);                                          \
    __builtin_amdgcn_s_setprio(1);                                              \
    _Pragma("unroll")                                                           \
    for (int i_ = 0; i_ < 4; ++i_)                                              \
        _Pragma("unroll")                                                       \
        for (int j_ = 0; j_ < 2; ++j_) {                                        \
            acc[(mh) * 4 + i_][(nh) * 2 + j_] =                                 \
                __builtin_amdgcn_mfma_f32_16x16x32_f16(                         \
                    af[i_][0], bf[j_][0], acc[(mh) * 4 + i_][(nh) * 2 + j_],    \
                    0, 0, 0);                                                   \
            acc[(mh) * 4 + i_][(nh) * 2 + j_] =                                 \
                __builtin_amdgcn_mfma_f32_16x16x32_f16(                         \
                    af[i_][1], bf[j_][1], acc[(mh) * 4 + i_][(nh) * 2 + j_],    \
                    0, 0, 0);                                                   \
        }                                                                       \
    __builtin_amdgcn_s_setprio(0);                                              \
    VM_STMT;                                                                    \
    __builtin_amdgcn_s_barrier();                                               \
    __builtin_amdgcn_sched_barrier(0);                                          \
} while (0)

    // running per-point top2 across the two 256-code passes (threads 0..255)
    float rv1 = 3.0e38f, rv2 = 3.0e38f;
    int   ri1 = 0x7fffffff, ri2 = 0x7fffffff;

    // epilogue scratch overlay on buf0 A region (16 KB; reused between passes)
    float* sc1 = (float*)smem;
    float* sc2 = sc1 + 1024;
    int*   si1 = (int*)(sc2 + 1024);
    int*   si2 = si1 + 1024;

#pragma unroll 1
    for (int nt = 0; nt < 2; ++nt) {
        const int kbase = nsplit * 512 + nt * 256;
        const _Float16* gB = B3 + (size_t)(kbase + srow) * 512 + sc;

        f32x4 acc[8][4];
#pragma unroll
        for (int mi = 0; mi < 8; ++mi)
#pragma unroll
            for (int ni = 0; ni < 4; ++ni)
                acc[mi][ni] = (f32x4){0.f, 0.f, 0.f, 0.f};

        // ---- prologue: tile0 fully + A0/A2 of tile1 stay in flight
        STAGE_A(0, 0); STAGE_A(2, 0); STAGE_A(1, 0); STAGE_A(3, 0);
        STAGE_B(0, 0); STAGE_B(1, 0); STAGE_B(2, 0); STAGE_B(3, 0);
        STAGE_A(0, 1); STAGE_A(2, 1);
        asm volatile("s_waitcnt vmcnt(2)" ::: "memory");
        __builtin_amdgcn_s_barrier();
        __builtin_amdgcn_sched_barrier(0);

#pragma unroll 1
        for (int g = 0; g < 8; ++g) {
            const int bufo = (g & 1) * 32768;
            PHASE(0, 0,
                  { if (g < 7) { STAGE_A(1, g + 1); STAGE_A(3, g + 1); } },
                  {});
            PHASE(0, 1,
                  { if (g < 7) { STAGE_B(0, g + 1); STAGE_B(1, g + 1); } },
                  {});
            PHASE(1, 0,
                  { if (g < 7) { STAGE_B(2, g + 1); STAGE_B(3, g + 1); } },
                  {});
            PHASE(1, 1,
                  { if (g < 6) { STAGE_A(0, g + 2); STAGE_A(2, g + 2); } },
                  { if (g < 6) asm volatile("s_waitcnt vmcnt(2)" ::: "memory");
                    else if (g == 6) asm volatile("s_waitcnt vmcnt(0)" ::: "memory"); });
        }

        // ---- fold: scores -> per-lane top2-of-4(ni) -> 16-lane merge -> LDS
        const int kb2 = kbase + wn * 64;
        float cn[4];
#pragma unroll
        for (int ni = 0; ni < 4; ++ni) cn[ni] = cnorm[kb2 + ni * 16 + m16];

#pragma unroll
        for (int mi = 0; mi < 8; ++mi) {
#pragma unroll
            for (int r = 0; r < 4; ++r) {
                float a1 = 3.0e38f, a2 = 3.0e38f;
                int   b1 = 0x7fffffff, b2 = 0x7fffffff;
#pragma unroll
                for (int ni = 0; ni < 4; ++ni) {      // k ascending: lowest wins ties
                    const float s = fmaf(-2.0f, acc[mi][ni][r], cn[ni]);
                    const int k = kb2 + ni * 16 + m16;
                    if (s < a1) { a2 = a1; b2 = b1; a1 = s; b1 = k; }
                    else if (s < a2) { a2 = s; b2 = k; }
                }
#pragma unroll
                for (int m = 1; m < 16; m <<= 1) {
                    const float c1 = __shfl_xor(a1, m, 64);
                    const int   d1 = __shfl_xor(b1, m, 64);
                    const float c2 = __shfl_xor(a2, m, 64);
                    const int   d2 = __shfl_xor(b2, m, 64);
                    top2_merge(a1, b1, a2, b2, c1, d1, c2, d2);
                }
                if ((l & 15) == 0) {
                    const int pr = wm * 128 + mi * 16 + qq * 4 + r;   // 0..255
                    sc1[pr * 4 + wn] = a1; si1[pr * 4 + wn] = b1;
                    sc2[pr * 4 + wn] = a2; si2[pr * 4 + wn] = b2;
                }
            }
        }
        __syncthreads();
        if (tid < 256) {
            float a1 = sc1[tid * 4], a2 = sc2[tid * 4];
            int   b1 = si1[tid * 4], b2 = si2[tid * 4];
#pragma unroll
            for (int gg = 1; gg < 4; ++gg)
                top2_merge(a1, b1, a2, b2, sc1[tid * 4 + gg], si1[tid * 4 + gg],
                           sc2[tid * 4 + gg], si2[tid * 4 + gg]);
            top2_merge(rv1, ri1, rv2, ri2, a1, b1, a2, b2);
        }
        __syncthreads();   // scratch reads done before next pass re-stages buf0
    }

    if (tid < 256) {
        const size_t o = (size_t)nsplit * N_PTS + pbase + tid;
        pv1[o] = rv1; pi1[o] = ri1;
        pv2[o] = rv2; pi2[o] = ri2;
    }
#undef STAGE_A
#undef STAGE_B
#undef PHASE
}

// ---------------------------------------------------------------- gather
// UNCHANGED from R7 (verified): parallel split merge + fp64 rescore of
// near-ties + fused gather/histogram/loss.
__global__ __launch_bounds__(128) void gather_kernel(
    const float* __restrict__ z_e, const float* __restrict__ cb,
    const float* __restrict__ pv1, const int* __restrict__ pi1,
    const float* __restrict__ pv2, const int* __restrict__ pi2,
    float* __restrict__ out_q, float* __restrict__ out_idx,
    unsigned int* __restrict__ counts, float* __restrict__ psums) {
    const int p = blockIdx.x;
    const int t = threadIdx.x;

    __shared__ float sv1[NSPLIT], sv2[NSPLIT];
    __shared__ int   si1[NSPLIT], si2[NSPLIT];
    if (t < NSPLIT) {
        const size_t o = (size_t)t * N_PTS + p;
        sv1[t] = pv1[o]; si1[t] = pi1[o];
        sv2[t] = pv2[o]; si2[t] = pi2[o];
    }
    __syncthreads();

    float bv = 3.0e38f; int bi = 0x7fffffff;
#pragma unroll
    for (int s = 0; s < NSPLIT; ++s) {
        const float v = sv1[s];
        const int i = si1[s];
        if (v < bv || (v == bv && i < bi)) { bv = v; bi = i; }
    }
    float second = 3.0e38f;
    int cand[8]; int nc = 1; cand[0] = bi;
#pragma unroll
    for (int s = 0; s < NSPLIT; ++s) {
        const float v = sv1[s];
        const int i = si1[s];
        const float w2 = sv2[s];
        const int j = si2[s];
        if (i != bi) {
            if (v < second) second = v;
            if (v <= bv + MARGIN && nc < 8) cand[nc++] = i;
        }
        if (j != bi) {
            if (w2 < second) second = w2;
            if (w2 <= bv + MARGIN && nc < 8) cand[nc++] = j;
        }
    }

    __shared__ double dred[2];
    if (second - bv <= MARGIN && nc > 1) {     // block-uniform condition
        double bestv = 1.0e300; int besti = 0x7fffffff;
        for (int c = 0; c < nc; ++c) {
            const int k = cand[c];
            double part = 0.0;
#pragma unroll
            for (int j = 0; j < 4; ++j) {
                const int d = t * 4 + j;
                const double cv = (double)cb[(size_t)k * DIM + d];
                const double zv = (double)z_e[(size_t)p * DIM + d];
                part += cv * cv - 2.0 * zv * cv;
            }
#pragma unroll
            for (int o = 32; o > 0; o >>= 1) part += __shfl_down(part, o, 64);
            if ((t & 63) == 0) dred[t >> 6] = part;
            __syncthreads();
            const double s = dred[0] + dred[1];
            __syncthreads();
            if (s < bestv || (s == bestv && k < besti)) { bestv = s; besti = k; }
        }
        bi = besti;
    }

    const float4 z = *(const float4*)(z_e + (size_t)p * DIM + t * 4);
    const float4 c = *(const float4*)(cb + (size_t)bi * DIM + t * 4);
    float4 d, o;
    d.x = c.x - z.x; d.y = c.y - z.y; d.z = c.z - z.z; d.w = c.w - z.w;
    o.x = z.x + d.x; o.y = z.y + d.y; o.z = z.z + d.z; o.w = z.w + d.w;
    *(float4*)(out_q + (size_t)p * DIM + t * 4) = o;
    float ls = d.x * d.x + d.y * d.y + d.z * d.z + d.w * d.w;
#pragma unroll
    for (int off = 32; off > 0; off >>= 1) ls += __shfl_down(ls, off, 64);
    __shared__ float red[2];
    if ((t & 63) == 0) red[t >> 6] = ls;
    __syncthreads();
    if (t == 0) {
        psums[p] = red[0] + red[1];
        out_idx[p] = (float)bi;
        atomicAdd(&counts[bi], 1u);
    }
}

// ---------------------------------------------------------------- finalize
__global__ __launch_bounds__(256) void finalize_kernel(
    const unsigned int* __restrict__ counts, const float* __restrict__ psums,
    float* __restrict__ out_scalars) {
    const int t = threadIdx.x;
    float ent = 0.0f;
    for (int b = t; b < K_CODES; b += 256) {
        const float pr = (float)counts[b] * (1.0f / 16384.0f);
        ent += pr * logf(pr + 1e-10f);
    }
    float ss = 0.0f;
    for (int i = t; i < N_PTS; i += 256) ss += psums[i];
#pragma unroll
    for (int off = 32; off > 0; off >>= 1) {
        ent += __shfl_down(ent, off, 64);
        ss += __shfl_down(ss, off, 64);
    }
    __shared__ float re[4], rs[4];
    if ((t & 63) == 0) { re[t >> 6] = ent; rs[t >> 6] = ss; }
    __syncthreads();
    if (t == 0) {
        const float loss = (rs[0] + rs[1] + rs[2] + rs[3]) * (1.0f / NELEM_F);
        out_scalars[0] = loss;
        out_scalars[1] = loss;
        out_scalars[2] = expf(-(re[0] + re[1] + re[2] + re[3]));
    }
}

// ================================================================ fallback
// round-1 pure fp32 path (used only if ws_size < WS_NEED)
#define FB_SPLIT 4
#define FB_KS    (K_CODES / FB_SPLIT)
#define FB_MT    128
#define FB_KT    128
#define FB_DT    32
#define FB_PITCH 36

__global__ __launch_bounds__(256, 2) void fb_dist_argmin_kernel(
    const float* __restrict__ z_e, const float* __restrict__ cb,
    const float* __restrict__ cnorm,
    float* __restrict__ pmin, int* __restrict__ pidx) {
    __shared__ float xs[FB_MT * FB_PITCH];
    __shared__ float cs[FB_KT * FB_PITCH];
    const int tid = threadIdx.x;
    const int tx = tid & 15, ty = tid >> 4;
    const int pbase = blockIdx.x * FB_MT;
    const int kbase0 = blockIdx.y * FB_KS;
    const int scol = (tid & 7) * 4, srow0 = tid >> 3;
    float mn[8], acc[8][8];
    int mi[8];
#pragma unroll
    for (int i = 0; i < 8; ++i) { mn[i] = 3.0e38f; mi[i] = 0; }
    for (int kt = 0; kt < FB_KS / FB_KT; ++kt) {
        const int kbase = kbase0 + kt * FB_KT;
#pragma unroll
        for (int i = 0; i < 8; ++i)
#pragma unroll
            for (int j = 0; j < 8; ++j) acc[i][j] = 0.0f;
        for (int dc = 0; dc < DIM / FB_DT; ++dc) {
            const int dbase = dc * FB_DT;
            __syncthreads();
#pragma unroll
            for (int it = 0; it < 4; ++it) {
                const int row = srow0 + it * 32;
                *(float4*)(xs + row * FB_PITCH + scol) =
                    *(const float4*)(z_e + (size_t)(pbase + row) * DIM + dbase + scol);
                *(float4*)(cs + row * FB_PITCH + scol) =
                    *(const float4*)(cb + (size_t)(kbase + row) * DIM + dbase + scol);
            }
            __syncthreads();
#pragma unroll 2
            for (int dd = 0; dd < FB_DT; dd += 4) {
                float4 xv[8], cv[8];
#pragma unroll
                for (int i = 0; i < 8; ++i)
                    xv[i] = *(const float4*)(xs + (ty + 16 * i) * FB_PITCH + dd);
#pragma unroll
                for (int j = 0; j < 8; ++j)
                    cv[j] = *(const float4*)(cs + (tx + 16 * j) * FB_PITCH + dd);
#pragma unroll
                for (int i = 0; i < 8; ++i)
#pragma unroll
                    for (int j = 0; j < 8; ++j)
                        acc[i][j] += xv[i].x * cv[j].x + xv[i].y * cv[j].y +
                                     xv[i].z * cv[j].z + xv[i].w * cv[j].w;
            }
        }
#pragma unroll
        for (int j = 0; j < 8; ++j) {
            const int k = kbase + tx + 16 * j;
            const float cn = cnorm[k];
#pragma unroll
            for (int i = 0; i < 8; ++i) {
                const float s = cn - 2.0f * acc[i][j];
                if (s < mn[i]) { mn[i] = s; mi[i] = k; }
            }
        }
    }
    float* rmin = xs;
    int* ridx = (int*)cs;
    __syncthreads();
#pragma unroll
    for (int i = 0; i < 8; ++i) {
        const int p = ty + 16 * i;
        rmin[p * 16 + tx] = mn[i];
        ridx[p * 16 + tx] = mi[i];
    }
    __syncthreads();
    if (tid < FB_MT) {
        float best = rmin[tid * 16];
        int bi = ridx[tid * 16];
#pragma unroll
        for (int t = 1; t < 16; ++t) {
            const float v = rmin[tid * 16 + t];
            const int k2 = ridx[tid * 16 + t];
            if (v < best || (v == best && k2 < bi)) { best = v; bi = k2; }
        }
        pmin[(size_t)blockIdx.y * N_PTS + pbase + tid] = best;
        pidx[(size_t)blockIdx.y * N_PTS + pbase + tid] = bi;
    }
}

__global__ __launch_bounds__(128) void fb_gather_kernel(
    const float* __restrict__ z_e, const float* __restrict__ cb,
    const float* __restrict__ pmin, const int* __restrict__ pidx,
    float* __restrict__ out_q, float* __restrict__ out_idx,
    unsigned int* __restrict__ counts, float* __restrict__ psums) {
    const int p = blockIdx.x;
    const int t = threadIdx.x;
    float best = pmin[p];
    int bi = pidx[p];
#pragma unroll
    for (int s = 1; s < FB_SPLIT; ++s) {
        const float v = pmin[(size_t)s * N_PTS + p];
        const int k2 = pidx[(size_t)s * N_PTS + p];
        if (v < best || (v == best && k2 < bi)) { best = v; bi = k2; }
    }
    const float4 z = *(const float4*)(z_e + (size_t)p * DIM + t * 4);
    const float4 c = *(const float4*)(cb + (size_t)bi * DIM + t * 4);
    float4 d, o;
    d.x = c.x - z.x; d.y = c.y - z.y; d.z = c.z - z.z; d.w = c.w - z.w;
    o.x = z.x + d.x; o.y = z.y + d.y; o.z = z.z + d.z; o.w = z.w + d.w;
    *(float4*)(out_q + (size_t)p * DIM + t * 4) = o;
    float ls = d.x * d.x + d.y * d.y + d.z * d.z + d.w * d.w;
#pragma unroll
    for (int off = 32; off > 0; off >>= 1) ls += __shfl_down(ls, off, 64);
    __shared__ float red[2];
    if ((t & 63) == 0) red[t >> 6] = ls;
    __syncthreads();
    if (t == 0) {
        psums[p] = red[0] + red[1];
        out_idx[p] = (float)bi;
        atomicAdd(&counts[bi], 1u);
    }
}

// ================================================================ launch
extern "C" void kernel_launch(void* const* d_in, const int* in_sizes, int n_in,
                              void* d_out, int out_size, void* d_ws, size_t ws_size,
                              hipStream_t stream) {
    const float* z_e = (const float*)d_in[0];
    const float* cb  = (const float*)d_in[1];
    float* out = (float*)d_out;
    char* ws = (char*)d_ws;

    if (ws_size >= WS_NEED) {
        _Float16* A3      = (_Float16*)(ws + OFF_A3);
        _Float16* B3      = (_Float16*)(ws + OFF_B3);
        float* cnorm      = (float*)(ws + OFF_CN);
        float* pv1        = (float*)(ws + OFF_PV1);
        int* pi1          = (int*)(ws + OFF_PI1);
        float* pv2        = (float*)(ws + OFF_PV2);
        int* pi2          = (int*)(ws + OFF_PI2);
        float* psums      = (float*)(ws + OFF_PSUM);
        unsigned int* cnt = (unsigned int*)(ws + OFF_CNT);

        prep_all<<<N_PTS + K_CODES, 128, 0, stream>>>(z_e, cb, A3, B3, cnorm, cnt);
        dim3 g(N_PTS / 256, NSPLIT);                   // 64 x 16 blocks, 512 thr
        score_kernel<<<g, 512, 0, stream>>>(A3, B3, cnorm, pv1, pi1, pv2, pi2);
        gather_kernel<<<N_PTS, 128, 0, stream>>>(z_e, cb, pv1, pi1, pv2, pi2,
                                                 out, out + OUT0_N, cnt, psums);
        finalize_kernel<<<1, 256, 0, stream>>>(cnt, psums, out + OUT0_N + N_PTS);
    } else {
        // round-1 fp32 fallback (<700 KB ws)
        float* cnorm      = (float*)ws;
        float* pmin       = (float*)(ws + 32768);
        int* pidx         = (int*)(ws + 32768 + 262144);
        unsigned int* cnt = (unsigned int*)(ws + 32768 + 2 * 262144);
        float* psums      = (float*)(ws + 32768 + 2 * 262144 + 32768);

        hipMemsetAsync(cnt, 0, 32768, stream);
        cnorm_kernel<<<K_CODES, 128, 0, stream>>>(cb, cnorm);
        dim3 grid1(N_PTS / FB_MT, FB_SPLIT);
        fb_dist_argmin_kernel<<<grid1, 256, 0, stream>>>(z_e, cb, cnorm, pmin, pidx);
        fb_gather_kernel<<<N_PTS, 128, 0, stream>>>(z_e, cb, pmin, pidx,
                                                    out, out + OUT0_N, cnt, psums);
        finalize_kernel<<<1, 256, 0, stream>>>(cnt, psums, out + OUT0_N + N_PTS);
    }
}

// Round 3
// 756.044 us; speedup vs baseline: 1.0079x; 1.0079x over previous
//
#include <hip/hip_runtime.h>

// ---------------------------------------------------------------------------
// VectorQuantizer: N=16384 points x K=8192 codes x D=512 fp32.
// R10: score GEMM = R7's fragment-read-economical tile body (af/bf read ONCE
// per K-tile, 4x4 acc/wave = 64 regs) + depth-2 software pipeline:
//   - BM=256 x BN=128, 8 waves (4M x 2N), wave tile 64x64
//   - 3 rotating LDS slots (48 KB each, 144 KB total), stage tile g+2 while
//     computing tile g via global_load_lds w=16 (pre-swizzled source)
//   - ONE raw s_barrier per K-tile, steady-state s_waitcnt vmcnt(6), never 0
//   - 4 code-passes per split fused into one 32-tile pipeline (no restarts);
//     pass-boundary fold overlays scratch on the provably-idle slot
// R9 post-mortem: quadrant-phasing doubled LDS read traffic (48KB/wave/tile,
// 21.8 FLOP/B) -> ds_read-bound, MfmaUtil 8.6%. R10 restores 32.8 FLOP/B.
// Fallback (small ws): round-1 pure-fp32 VALU kernel (known-correct).
// ---------------------------------------------------------------------------

#define N_PTS   16384
#define DIM     512
#define K_CODES 8192
#define NSPLIT  16                    // code splits (512 codes each)
#define OUT0_N  (N_PTS * DIM)
#define NELEM_F (8388608.0f)
#define MARGIN  1.5e-2f

typedef _Float16 half8 __attribute__((ext_vector_type(8)));
typedef _Float16 f16x4 __attribute__((ext_vector_type(4)));
typedef float    f32x4 __attribute__((ext_vector_type(4)));

// fast-path workspace layout (bytes) — unchanged from R7
#define SZ_A3    (16384UL * 512 * 2)               // 16.8 MB
#define SZ_B3    (8192UL * 512 * 2)                // 8.4 MB
#define OFF_A3   0UL
#define OFF_B3   (OFF_A3 + SZ_A3)
#define OFF_CN   (OFF_B3 + SZ_B3)                  // cnorm 32 KB
#define OFF_PV1  (OFF_CN + 32768UL)
#define SZ_P     (16UL * 16384 * 4)                // 1 MB each
#define OFF_PI1  (OFF_PV1 + SZ_P)
#define OFF_PV2  (OFF_PI1 + SZ_P)
#define OFF_PI2  (OFF_PV2 + SZ_P)
#define OFF_PSUM (OFF_PI2 + SZ_P)                  // psums 64 KB
#define OFF_CNT  (OFF_PSUM + 65536UL)              // counts 32 KB
#define WS_NEED  (OFF_CNT + 32768UL)

#define GLOAD_LDS16(g, l) \
    __builtin_amdgcn_global_load_lds( \
        (const __attribute__((address_space(1))) unsigned int*)(g), \
        (__attribute__((address_space(3))) unsigned int*)(l), 16, 0, 0)

// ---------------------------------------------------------------- prep (fused)
__global__ __launch_bounds__(128) void prep_all(const float* __restrict__ z_e,
                                                const float* __restrict__ cb,
                                                _Float16* __restrict__ A3,
                                                _Float16* __restrict__ B3,
                                                float* __restrict__ cnorm,
                                                unsigned int* __restrict__ counts) {
    const int b = blockIdx.x;
    const int t = threadIdx.x;
    if (b < 64) counts[b * 128 + t] = 0u;
    if (b < N_PTS) {
        const long r = b;
        const int d = t * 4;
        const float4 v = *(const float4*)(z_e + r * DIM + d);
        f16x4 h;
        h[0] = (_Float16)v.x; h[1] = (_Float16)v.y;
        h[2] = (_Float16)v.z; h[3] = (_Float16)v.w;
        *(f16x4*)(A3 + r * 512 + d) = h;
    } else {
        const long r = b - N_PTS;
        const int d = t * 4;
        const float4 v = *(const float4*)(cb + r * DIM + d);
        f16x4 h;
        h[0] = (_Float16)v.x; h[1] = (_Float16)v.y;
        h[2] = (_Float16)v.z; h[3] = (_Float16)v.w;
        *(f16x4*)(B3 + r * 512 + d) = h;
        float s = v.x * v.x + v.y * v.y + v.z * v.z + v.w * v.w;
#pragma unroll
        for (int o = 32; o > 0; o >>= 1) s += __shfl_down(s, o, 64);
        __shared__ float red[2];
        if ((t & 63) == 0) red[t >> 6] = s;
        __syncthreads();
        if (t == 0) cnorm[r] = red[0] + red[1];
    }
}

// ---------------------------------------------------------------- cnorm (fallback)
__global__ __launch_bounds__(128) void cnorm_kernel(const float* __restrict__ cb,
                                                    float* __restrict__ cnorm) {
    const int k = blockIdx.x;
    const int t = threadIdx.x;
    const float4 v = *(const float4*)(cb + (size_t)k * DIM + t * 4);
    float s = v.x * v.x + v.y * v.y + v.z * v.z + v.w * v.w;
#pragma unroll
    for (int o = 32; o > 0; o >>= 1) s += __shfl_down(s, o, 64);
    __shared__ float red[2];
    if ((t & 63) == 0) red[t >> 6] = s;
    __syncthreads();
    if (t == 0) cnorm[k] = red[0] + red[1];
}

// ---------------------------------------------------------------- top2 merge
__device__ __forceinline__ void top2_merge(float& a1, int& b1, float& a2, int& b2,
                                           const float c1, const int d1,
                                           const float c2, const int d2) {
    if (c1 < a1 || (c1 == a1 && d1 < b1)) {
        if (a1 < c2 || (a1 == c2 && b1 < d2)) { a2 = a1; b2 = b1; }
        else { a2 = c2; b2 = d2; }
        a1 = c1; b1 = d1;
    } else {
        if (c1 < a2 || (c1 == a2 && d1 < b2)) { a2 = c1; b2 = d1; }
    }
}

// ---------------------------------------------------------------- score GEMM
// 256x128 tile, BK=64, 512 threads = 8 waves (4M x 2N), wave tile 64x64 via
// 4x4 of 16x16x32 f16 MFMA (acc = 64 VGPRs). 3 rotating LDS slots of 48 KB
// (A 256x64 = 32 KB + B 128x64 = 16 KB), 16B-chunk XOR swizzle
// LDS[r][c] = G[r][c ^ (r&7)] (pre-swizzled global source; conflict-free
// b128 reads, verified R4-R9). 32 tiles per block (4 code passes x 8 K-tiles)
// run as ONE pipeline: tile t reads slot t%3 while staging tile t+2 into
// slot (t+2)%3 (6 global_load_lds units of 8 KB). End of tile t:
// vmcnt(6) (t<=29) / vmcnt(0) (t==30) + one raw s_barrier. Per-pass top2
// fold overlays 8 KB scratch on slot t%3 (idle between barrier and t+1).
__global__ __launch_bounds__(512, 2) void score_kernel(
    const _Float16* __restrict__ A3, const _Float16* __restrict__ B3,
    const float* __restrict__ cnorm,
    float* __restrict__ pv1, int* __restrict__ pi1,
    float* __restrict__ pv2, int* __restrict__ pi2) {
    __shared__ _Float16 smem[73728];    // 144 KiB = 3 slots x 24576 halves

    const int tid = threadIdx.x;
    const int w   = tid >> 6;           // wave 0..7
    const int l   = tid & 63;
    const int wm  = w >> 1;             // 0..3 (row quarter)
    const int wn  = w & 1;              // 0..1 (col half)
    const int m16 = l & 15;
    const int qq  = l >> 4;
    const int x7  = l & 7;
    const int pbase  = blockIdx.x * 256;
    const int nsplit = blockIdx.y;      // 0..15

    // staging: thread -> (row tid>>3, linear chunk tid&7) of a 64-row unit;
    // global source chunk pre-swizzled so LDS[r][c] = G[r][c^(r&7)].
    const int srow = tid >> 3;          // 0..63
    const int sc   = ((tid & 7) ^ (srow & 7)) * 8;        // halves
    const _Float16* gA  = A3 + (size_t)(pbase + srow) * 512 + sc;
    const _Float16* gB0 = B3 + (size_t)(nsplit * 512 + srow) * 512 + sc;

    // read-side bases
    const int rA = wm * 64 + m16;       // A row base (+ mi*16), 0..255
    const int rB = wn * 64 + m16;       // B row base (+ ni*16), 0..127
    const int k0 = (qq ^ x7) * 8;       // ks=0 chunk offset (halves); ks=1 -> ^32

    // stage tile ts (global tile index 0..31) into slot ts%3.
    // A: 4 units of 64 rows; B: 2 units of 64 rows. 6 gload_lds / thread.
#define STAGE_TILE(ts) do {                                                     \
    const int slotb_ = ((ts) % 3) * 24576;                                      \
    const long ko_   = (long)(((ts) & 7) * 64);                                 \
    const long bro_  = (long)(((ts) >> 3) * 128) * 512;                         \
    GLOAD_LDS16(gA + 0 * 32768 + ko_, &smem[slotb_ + 0 * 4096 + w * 512]);      \
    GLOAD_LDS16(gA + 1 * 32768 + ko_, &smem[slotb_ + 1 * 4096 + w * 512]);      \
    GLOAD_LDS16(gA + 2 * 32768 + ko_, &smem[slotb_ + 2 * 4096 + w * 512]);      \
    GLOAD_LDS16(gA + 3 * 32768 + ko_, &smem[slotb_ + 3 * 4096 + w * 512]);      \
    GLOAD_LDS16(gB0 + bro_ + 0 * 32768 + ko_,                                   \
                &smem[slotb_ + 16384 + 0 * 4096 + w * 512]);                    \
    GLOAD_LDS16(gB0 + bro_ + 1 * 32768 + ko_,                                   \
                &smem[slotb_ + 16384 + 1 * 4096 + w * 512]);                    \
} while (0)

    // running per-point top2 across the four 128-code passes (threads 0..255)
    float rv1 = 3.0e38f, rv2 = 3.0e38f;
    int   ri1 = 0x7fffffff, ri2 = 0x7fffffff;

    // ---- prologue: tiles 0 and 1 in flight, wait for tile 0
    STAGE_TILE(0);
    STAGE_TILE(1);
    asm volatile("s_waitcnt vmcnt(6)" ::: "memory");
    __builtin_amdgcn_s_barrier();

#pragma unroll 1
    for (int nt = 0; nt < 4; ++nt) {
        const int kbase = nsplit * 512 + nt * 128;

        f32x4 acc[4][4];
#pragma unroll
        for (int mi = 0; mi < 4; ++mi)
#pragma unroll
            for (int ni = 0; ni < 4; ++ni)
                acc[mi][ni] = (f32x4){0.f, 0.f, 0.f, 0.f};

#pragma unroll 1
        for (int g = 0; g < 8; ++g) {
            const int t_ = nt * 8 + g;
            // stage tile t_+2 (issue loads FIRST so they overlap the MFMAs)
            if (t_ + 2 < 32) STAGE_TILE(t_ + 2);

            // read fragments ONCE per K-tile from slot t_%3
            const int rb = (t_ % 3) * 24576;
            half8 af[4][2], bf[4][2];
#pragma unroll
            for (int mi = 0; mi < 4; ++mi) {
                const int r_ = rb + (rA + mi * 16) * 64;
                af[mi][0] = *(const half8*)&smem[r_ + k0];
                af[mi][1] = *(const half8*)&smem[r_ + (k0 ^ 32)];
            }
#pragma unroll
            for (int ni = 0; ni < 4; ++ni) {
                const int r_ = rb + 16384 + (rB + ni * 16) * 64;
                bf[ni][0] = *(const half8*)&smem[r_ + k0];
                bf[ni][1] = *(const half8*)&smem[r_ + (k0 ^ 32)];
            }

            __builtin_amdgcn_s_setprio(1);
#pragma unroll
            for (int ks = 0; ks < 2; ++ks)
#pragma unroll
                for (int mi = 0; mi < 4; ++mi)
#pragma unroll
                    for (int ni = 0; ni < 4; ++ni)
                        acc[mi][ni] = __builtin_amdgcn_mfma_f32_16x16x32_f16(
                            af[mi][ks], bf[ni][ks], acc[mi][ni], 0, 0, 0);
            __builtin_amdgcn_s_setprio(0);

            // counted waits: ensure tile t_+1 is resident before next iter.
            if (t_ < 30)       asm volatile("s_waitcnt vmcnt(6)" ::: "memory");
            else if (t_ == 30) asm volatile("s_waitcnt vmcnt(0)" ::: "memory");
            __builtin_amdgcn_s_barrier();
        }

        // ---- per-pass fold: scores -> per-lane top2-of-4(ni) -> 16-lane
        // merge -> scratch (overlay on slot (nt*8+7)%3, idle until t_+1 stages)
        {
            const int scrb = ((nt * 8 + 7) % 3) * 24576;
            float* sc1 = (float*)&smem[scrb];
            float* sc2 = sc1 + 512;
            int*   si1 = (int*)(sc2 + 512);
            int*   si2 = si1 + 512;

            const int kb2 = kbase + wn * 64;
            float cn[4];
#pragma unroll
            for (int ni = 0; ni < 4; ++ni) cn[ni] = cnorm[kb2 + ni * 16 + m16];

#pragma unroll
            for (int mi = 0; mi < 4; ++mi) {
#pragma unroll
                for (int r = 0; r < 4; ++r) {
                    float a1 = 3.0e38f, a2 = 3.0e38f;
                    int   b1 = 0x7fffffff, b2 = 0x7fffffff;
#pragma unroll
                    for (int ni = 0; ni < 4; ++ni) {  // k ascending: low k wins ties
                        const float s = fmaf(-2.0f, acc[mi][ni][r], cn[ni]);
                        const int k = kb2 + ni * 16 + m16;
                        if (s < a1) { a2 = a1; b2 = b1; a1 = s; b1 = k; }
                        else if (s < a2) { a2 = s; b2 = k; }
                    }
#pragma unroll
                    for (int m = 1; m < 16; m <<= 1) {
                        const float c1 = __shfl_xor(a1, m, 64);
                        const int   d1 = __shfl_xor(b1, m, 64);
                        const float c2 = __shfl_xor(a2, m, 64);
                        const int   d2 = __shfl_xor(b2, m, 64);
                        top2_merge(a1, b1, a2, b2, c1, d1, c2, d2);
                    }
                    if ((l & 15) == 0) {
                        const int pr = wm * 64 + mi * 16 + qq * 4 + r;  // 0..255
                        sc1[pr * 2 + wn] = a1; si1[pr * 2 + wn] = b1;
                        sc2[pr * 2 + wn] = a2; si2[pr * 2 + wn] = b2;
                    }
                }
            }
            __syncthreads();
            if (tid < 256) {
                float a1 = sc1[tid * 2], a2 = sc2[tid * 2];
                int   b1 = si1[tid * 2], b2 = si2[tid * 2];
                top2_merge(a1, b1, a2, b2, sc1[tid * 2 + 1], si1[tid * 2 + 1],
                           sc2[tid * 2 + 1], si2[tid * 2 + 1]);
                top2_merge(rv1, ri1, rv2, ri2, a1, b1, a2, b2);
            }
            __syncthreads();   // scratch reads done before t_+1 stages over it
        }
    }

    if (tid < 256) {
        const size_t o = (size_t)nsplit * N_PTS + pbase + tid;
        pv1[o] = rv1; pi1[o] = ri1;
        pv2[o] = rv2; pi2[o] = ri2;
    }
#undef STAGE_TILE
}

// ---------------------------------------------------------------- gather
// UNCHANGED from R7 (verified): parallel split merge + fp64 rescore of
// near-ties + fused gather/histogram/loss.
__global__ __launch_bounds__(128) void gather_kernel(
    const float* __restrict__ z_e, const float* __restrict__ cb,
    const float* __restrict__ pv1, const int* __restrict__ pi1,
    const float* __restrict__ pv2, const int* __restrict__ pi2,
    float* __restrict__ out_q, float* __restrict__ out_idx,
    unsigned int* __restrict__ counts, float* __restrict__ psums) {
    const int p = blockIdx.x;
    const int t = threadIdx.x;

    __shared__ float sv1[NSPLIT], sv2[NSPLIT];
    __shared__ int   si1[NSPLIT], si2[NSPLIT];
    if (t < NSPLIT) {
        const size_t o = (size_t)t * N_PTS + p;
        sv1[t] = pv1[o]; si1[t] = pi1[o];
        sv2[t] = pv2[o]; si2[t] = pi2[o];
    }
    __syncthreads();

    float bv = 3.0e38f; int bi = 0x7fffffff;
#pragma unroll
    for (int s = 0; s < NSPLIT; ++s) {
        const float v = sv1[s];
        const int i = si1[s];
        if (v < bv || (v == bv && i < bi)) { bv = v; bi = i; }
    }
    float second = 3.0e38f;
    int cand[8]; int nc = 1; cand[0] = bi;
#pragma unroll
    for (int s = 0; s < NSPLIT; ++s) {
        const float v = sv1[s];
        const int i = si1[s];
        const float w2 = sv2[s];
        const int j = si2[s];
        if (i != bi) {
            if (v < second) second = v;
            if (v <= bv + MARGIN && nc < 8) cand[nc++] = i;
        }
        if (j != bi) {
            if (w2 < second) second = w2;
            if (w2 <= bv + MARGIN && nc < 8) cand[nc++] = j;
        }
    }

    __shared__ double dred[2];
    if (second - bv <= MARGIN && nc > 1) {     // block-uniform condition
        double bestv = 1.0e300; int besti = 0x7fffffff;
        for (int c = 0; c < nc; ++c) {
            const int k = cand[c];
            double part = 0.0;
#pragma unroll
            for (int j = 0; j < 4; ++j) {
                const int d = t * 4 + j;
                const double cv = (double)cb[(size_t)k * DIM + d];
                const double zv = (double)z_e[(size_t)p * DIM + d];
                part += cv * cv - 2.0 * zv * cv;
            }
#pragma unroll
            for (int o = 32; o > 0; o >>= 1) part += __shfl_down(part, o, 64);
            if ((t & 63) == 0) dred[t >> 6] = part;
            __syncthreads();
            const double s = dred[0] + dred[1];
            __syncthreads();
            if (s < bestv || (s == bestv && k < besti)) { bestv = s; besti = k; }
        }
        bi = besti;
    }

    const float4 z = *(const float4*)(z_e + (size_t)p * DIM + t * 4);
    const float4 c = *(const float4*)(cb + (size_t)bi * DIM + t * 4);
    float4 d, o;
    d.x = c.x - z.x; d.y = c.y - z.y; d.z = c.z - z.z; d.w = c.w - z.w;
    o.x = z.x + d.x; o.y = z.y + d.y; o.z = z.z + d.z; o.w = z.w + d.w;
    *(float4*)(out_q + (size_t)p * DIM + t * 4) = o;
    float ls = d.x * d.x + d.y * d.y + d.z * d.z + d.w * d.w;
#pragma unroll
    for (int off = 32; off > 0; off >>= 1) ls += __shfl_down(ls, off, 64);
    __shared__ float red[2];
    if ((t & 63) == 0) red[t >> 6] = ls;
    __syncthreads();
    if (t == 0) {
        psums[p] = red[0] + red[1];
        out_idx[p] = (float)bi;
        atomicAdd(&counts[bi], 1u);
    }
}

// ---------------------------------------------------------------- finalize
__global__ __launch_bounds__(256) void finalize_kernel(
    const unsigned int* __restrict__ counts, const float* __restrict__ psums,
    float* __restrict__ out_scalars) {
    const int t = threadIdx.x;
    float ent = 0.0f;
    for (int b = t; b < K_CODES; b += 256) {
        const float pr = (float)counts[b] * (1.0f / 16384.0f);
        ent += pr * logf(pr + 1e-10f);
    }
    float ss = 0.0f;
    for (int i = t; i < N_PTS; i += 256) ss += psums[i];
#pragma unroll
    for (int off = 32; off > 0; off >>= 1) {
        ent += __shfl_down(ent, off, 64);
        ss += __shfl_down(ss, off, 64);
    }
    __shared__ float re[4], rs[4];
    if ((t & 63) == 0) { re[t >> 6] = ent; rs[t >> 6] = ss; }
    __syncthreads();
    if (t == 0) {
        const float loss = (rs[0] + rs[1] + rs[2] + rs[3]) * (1.0f / NELEM_F);
        out_scalars[0] = loss;
        out_scalars[1] = loss;
        out_scalars[2] = expf(-(re[0] + re[1] + re[2] + re[3]));
    }
}

// ================================================================ fallback
// round-1 pure fp32 path (used only if ws_size < WS_NEED)
#define FB_SPLIT 4
#define FB_KS    (K_CODES / FB_SPLIT)
#define FB_MT    128
#define FB_KT    128
#define FB_DT    32
#define FB_PITCH 36

__global__ __launch_bounds__(256, 2) void fb_dist_argmin_kernel(
    const float* __restrict__ z_e, const float* __restrict__ cb,
    const float* __restrict__ cnorm,
    float* __restrict__ pmin, int* __restrict__ pidx) {
    __shared__ float xs[FB_MT * FB_PITCH];
    __shared__ float cs[FB_KT * FB_PITCH];
    const int tid = threadIdx.x;
    const int tx = tid & 15, ty = tid >> 4;
    const int pbase = blockIdx.x * FB_MT;
    const int kbase0 = blockIdx.y * FB_KS;
    const int scol = (tid & 7) * 4, srow0 = tid >> 3;
    float mn[8], acc[8][8];
    int mi[8];
#pragma unroll
    for (int i = 0; i < 8; ++i) { mn[i] = 3.0e38f; mi[i] = 0; }
    for (int kt = 0; kt < FB_KS / FB_KT; ++kt) {
        const int kbase = kbase0 + kt * FB_KT;
#pragma unroll
        for (int i = 0; i < 8; ++i)
#pragma unroll
            for (int j = 0; j < 8; ++j) acc[i][j] = 0.0f;
        for (int dc = 0; dc < DIM / FB_DT; ++dc) {
            const int dbase = dc * FB_DT;
            __syncthreads();
#pragma unroll
            for (int it = 0; it < 4; ++it) {
                const int row = srow0 + it * 32;
                *(float4*)(xs + row * FB_PITCH + scol) =
                    *(const float4*)(z_e + (size_t)(pbase + row) * DIM + dbase + scol);
                *(float4*)(cs + row * FB_PITCH + scol) =
                    *(const float4*)(cb + (size_t)(kbase + row) * DIM + dbase + scol);
            }
            __syncthreads();
#pragma unroll 2
            for (int dd = 0; dd < FB_DT; dd += 4) {
                float4 xv[8], cv[8];
#pragma unroll
                for (int i = 0; i < 8; ++i)
                    xv[i] = *(const float4*)(xs + (ty + 16 * i) * FB_PITCH + dd);
#pragma unroll
                for (int j = 0; j < 8; ++j)
                    cv[j] = *(const float4*)(cs + (tx + 16 * j) * FB_PITCH + dd);
#pragma unroll
                for (int i = 0; i < 8; ++i)
#pragma unroll
                    for (int j = 0; j < 8; ++j)
                        acc[i][j] += xv[i].x * cv[j].x + xv[i].y * cv[j].y +
                                     xv[i].z * cv[j].z + xv[i].w * cv[j].w;
            }
        }
#pragma unroll
        for (int j = 0; j < 8; ++j) {
            const int k = kbase + tx + 16 * j;
            const float cn = cnorm[k];
#pragma unroll
            for (int i = 0; i < 8; ++i) {
                const float s = cn - 2.0f * acc[i][j];
                if (s < mn[i]) { mn[i] = s; mi[i] = k; }
            }
        }
    }
    float* rmin = xs;
    int* ridx = (int*)cs;
    __syncthreads();
#pragma unroll
    for (int i = 0; i < 8; ++i) {
        const int p = ty + 16 * i;
        rmin[p * 16 + tx] = mn[i];
        ridx[p * 16 + tx] = mi[i];
    }
    __syncthreads();
    if (tid < FB_MT) {
        float best = rmin[tid * 16];
        int bi = ridx[tid * 16];
#pragma unroll
        for (int t = 1; t < 16; ++t) {
            const float v = rmin[tid * 16 + t];
            const int k2 = ridx[tid * 16 + t];
            if (v < best || (v == best && k2 < bi)) { best = v; bi = k2; }
        }
        pmin[(size_t)blockIdx.y * N_PTS + pbase + tid] = best;
        pidx[(size_t)blockIdx.y * N_PTS + pbase + tid] = bi;
    }
}

__global__ __launch_bounds__(128) void fb_gather_kernel(
    const float* __restrict__ z_e, const float* __restrict__ cb,
    const float* __restrict__ pmin, const int* __restrict__ pidx,
    float* __restrict__ out_q, float* __restrict__ out_idx,
    unsigned int* __restrict__ counts, float* __restrict__ psums) {
    const int p = blockIdx.x;
    const int t = threadIdx.x;
    float best = pmin[p];
    int bi = pidx[p];
#pragma unroll
    for (int s = 1; s < FB_SPLIT; ++s) {
        const float v = pmin[(size_t)s * N_PTS + p];
        const int k2 = pidx[(size_t)s * N_PTS + p];
        if (v < best || (v == best && k2 < bi)) { best = v; bi = k2; }
    }
    const float4 z = *(const float4*)(z_e + (size_t)p * DIM + t * 4);
    const float4 c = *(const float4*)(cb + (size_t)bi * DIM + t * 4);
    float4 d, o;
    d.x = c.x - z.x; d.y = c.y - z.y; d.z = c.z - z.z; d.w = c.w - z.w;
    o.x = z.x + d.x; o.y = z.y + d.y; o.z = z.z + d.z; o.w = z.w + d.w;
    *(float4*)(out_q + (size_t)p * DIM + t * 4) = o;
    float ls = d.x * d.x + d.y * d.y + d.z * d.z + d.w * d.w;
#pragma unroll
    for (int off = 32; off > 0; off >>= 1) ls += __shfl_down(ls, off, 64);
    __shared__ float red[2];
    if ((t & 63) == 0) red[t >> 6] = ls;
    __syncthreads();
    if (t == 0) {
        psums[p] = red[0] + red[1];
        out_idx[p] = (float)bi;
        atomicAdd(&counts[bi], 1u);
    }
}

// ================================================================ launch
extern "C" void kernel_launch(void* const* d_in, const int* in_sizes, int n_in,
                              void* d_out, int out_size, void* d_ws, size_t ws_size,
                              hipStream_t stream) {
    const float* z_e = (const float*)d_in[0];
    const float* cb  = (const float*)d_in[1];
    float* out = (float*)d_out;
    char* ws = (char*)d_ws;

    if (ws_size >= WS_NEED) {
        _Float16* A3      = (_Float16*)(ws + OFF_A3);
        _Float16* B3      = (_Float16*)(ws + OFF_B3);
        float* cnorm      = (float*)(ws + OFF_CN);
        float* pv1        = (float*)(ws + OFF_PV1);
        int* pi1          = (int*)(ws + OFF_PI1);
        float* pv2        = (float*)(ws + OFF_PV2);
        int* pi2          = (int*)(ws + OFF_PI2);
        float* psums      = (float*)(ws + OFF_PSUM);
        unsigned int* cnt = (unsigned int*)(ws + OFF_CNT);

        prep_all<<<N_PTS + K_CODES, 128, 0, stream>>>(z_e, cb, A3, B3, cnorm, cnt);
        dim3 g(N_PTS / 256, NSPLIT);                   // 64 x 16 blocks, 512 thr
        score_kernel<<<g, 512, 0, stream>>>(A3, B3, cnorm, pv1, pi1, pv2, pi2);
        gather_kernel<<<N_PTS, 128, 0, stream>>>(z_e, cb, pv1, pi1, pv2, pi2,
                                                 out, out + OUT0_N, cnt, psums);
        finalize_kernel<<<1, 256, 0, stream>>>(cnt, psums, out + OUT0_N + N_PTS);
    } else {
        // round-1 fp32 fallback (<700 KB ws)
        float* cnorm      = (float*)ws;
        float* pmin       = (float*)(ws + 32768);
        int* pidx         = (int*)(ws + 32768 + 262144);
        unsigned int* cnt = (unsigned int*)(ws + 32768 + 2 * 262144);
        float* psums      = (float*)(ws + 32768 + 2 * 262144 + 32768);

        hipMemsetAsync(cnt, 0, 32768, stream);
        cnorm_kernel<<<K_CODES, 128, 0, stream>>>(cb, cnorm);
        dim3 grid1(N_PTS / FB_MT, FB_SPLIT);
        fb_dist_argmin_kernel<<<grid1, 256, 0, stream>>>(z_e, cb, cnorm, pmin, pidx);
        fb_gather_kernel<<<N_PTS, 128, 0, stream>>>(z_e, cb, pmin, pidx,
                                                    out, out + OUT0_N, cnt, psums);
        finalize_kernel<<<1, 256, 0, stream>>>(cnt, psums, out + OUT0_N + N_PTS);
    }
}

// Round 4
// 752.814 us; speedup vs baseline: 1.0122x; 1.0043x over previous
//
#include <hip/hip_runtime.h>

// ---------------------------------------------------------------------------
// VectorQuantizer: N=16384 points x K=8192 codes x D=512 fp32.
// R11: R10's depth-2 triple-buffered pipeline (verified absmax 0) with the
// REGISTER-BUDGET FIX. R8-R10 all clamped at ~667us / 8.7% MfmaUtil because
// hipcc capped the 512-thread builds at ~128 VGPR/wave (VGPR_Count 88-120)
// and spilled the K-loop working set to scratch; scratch shares vmcnt so
// every reload drained the prefetch queue (scratch mostly absorbed by L2 ->
// small WRITE_SIZE masked it). Fix: amdgpu_waves_per_eu(2,2) pins 2
// waves/SIMD -> 256-VGPR budget (HK's 8-wave kernels run ~249 VGPR this
// way). Also split fragment reads per-ks (32 live frag VGPRs, not 64).
// Fallback (small ws): round-1 pure-fp32 VALU kernel (known-correct).
// ---------------------------------------------------------------------------

#define N_PTS   16384
#define DIM     512
#define K_CODES 8192
#define NSPLIT  16                    // code splits (512 codes each)
#define OUT0_N  (N_PTS * DIM)
#define NELEM_F (8388608.0f)
#define MARGIN  1.5e-2f

typedef _Float16 half8 __attribute__((ext_vector_type(8)));
typedef _Float16 f16x4 __attribute__((ext_vector_type(4)));
typedef float    f32x4 __attribute__((ext_vector_type(4)));

// fast-path workspace layout (bytes) — unchanged from R7
#define SZ_A3    (16384UL * 512 * 2)               // 16.8 MB
#define SZ_B3    (8192UL * 512 * 2)                // 8.4 MB
#define OFF_A3   0UL
#define OFF_B3   (OFF_A3 + SZ_A3)
#define OFF_CN   (OFF_B3 + SZ_B3)                  // cnorm 32 KB
#define OFF_PV1  (OFF_CN + 32768UL)
#define SZ_P     (16UL * 16384 * 4)                // 1 MB each
#define OFF_PI1  (OFF_PV1 + SZ_P)
#define OFF_PV2  (OFF_PI1 + SZ_P)
#define OFF_PI2  (OFF_PV2 + SZ_P)
#define OFF_PSUM (OFF_PI2 + SZ_P)                  // psums 64 KB
#define OFF_CNT  (OFF_PSUM + 65536UL)              // counts 32 KB
#define WS_NEED  (OFF_CNT + 32768UL)

#define GLOAD_LDS16(g, l) \
    __builtin_amdgcn_global_load_lds( \
        (const __attribute__((address_space(1))) unsigned int*)(g), \
        (__attribute__((address_space(3))) unsigned int*)(l), 16, 0, 0)

// ---------------------------------------------------------------- prep (fused)
__global__ __launch_bounds__(128) void prep_all(const float* __restrict__ z_e,
                                                const float* __restrict__ cb,
                                                _Float16* __restrict__ A3,
                                                _Float16* __restrict__ B3,
                                                float* __restrict__ cnorm,
                                                unsigned int* __restrict__ counts) {
    const int b = blockIdx.x;
    const int t = threadIdx.x;
    if (b < 64) counts[b * 128 + t] = 0u;
    if (b < N_PTS) {
        const long r = b;
        const int d = t * 4;
        const float4 v = *(const float4*)(z_e + r * DIM + d);
        f16x4 h;
        h[0] = (_Float16)v.x; h[1] = (_Float16)v.y;
        h[2] = (_Float16)v.z; h[3] = (_Float16)v.w;
        *(f16x4*)(A3 + r * 512 + d) = h;
    } else {
        const long r = b - N_PTS;
        const int d = t * 4;
        const float4 v = *(const float4*)(cb + r * DIM + d);
        f16x4 h;
        h[0] = (_Float16)v.x; h[1] = (_Float16)v.y;
        h[2] = (_Float16)v.z; h[3] = (_Float16)v.w;
        *(f16x4*)(B3 + r * 512 + d) = h;
        float s = v.x * v.x + v.y * v.y + v.z * v.z + v.w * v.w;
#pragma unroll
        for (int o = 32; o > 0; o >>= 1) s += __shfl_down(s, o, 64);
        __shared__ float red[2];
        if ((t & 63) == 0) red[t >> 6] = s;
        __syncthreads();
        if (t == 0) cnorm[r] = red[0] + red[1];
    }
}

// ---------------------------------------------------------------- cnorm (fallback)
__global__ __launch_bounds__(128) void cnorm_kernel(const float* __restrict__ cb,
                                                    float* __restrict__ cnorm) {
    const int k = blockIdx.x;
    const int t = threadIdx.x;
    const float4 v = *(const float4*)(cb + (size_t)k * DIM + t * 4);
    float s = v.x * v.x + v.y * v.y + v.z * v.z + v.w * v.w;
#pragma unroll
    for (int o = 32; o > 0; o >>= 1) s += __shfl_down(s, o, 64);
    __shared__ float red[2];
    if ((t & 63) == 0) red[t >> 6] = s;
    __syncthreads();
    if (t == 0) cnorm[k] = red[0] + red[1];
}

// ---------------------------------------------------------------- top2 merge
__device__ __forceinline__ void top2_merge(float& a1, int& b1, float& a2, int& b2,
                                           const float c1, const int d1,
                                           const float c2, const int d2) {
    if (c1 < a1 || (c1 == a1 && d1 < b1)) {
        if (a1 < c2 || (a1 == c2 && b1 < d2)) { a2 = a1; b2 = b1; }
        else { a2 = c2; b2 = d2; }
        a1 = c1; b1 = d1;
    } else {
        if (c1 < a2 || (c1 == a2 && d1 < b2)) { a2 = c1; b2 = d1; }
    }
}

// ---------------------------------------------------------------- score GEMM
// 256x128 tile, BK=64, 512 threads = 8 waves (4M x 2N), wave tile 64x64 via
// 4x4 of 16x16x32 f16 MFMA (acc = 64 AGPRs). 3 rotating LDS slots of 48 KB
// (A 256x64 = 32 KB + B 128x64 = 16 KB), 16B-chunk XOR swizzle
// LDS[r][c] = G[r][c ^ (r&7)] (pre-swizzled global source; conflict-free
// b128 reads, verified R4-R10). 32 tiles per block (4 code passes x 8
// K-tiles) run as ONE pipeline: tile t reads slot t%3 while staging tile
// t+2 into slot (t+2)%3. End of tile t: vmcnt(6) (t<=29) / vmcnt(0) (t==30)
// + one raw s_barrier. Per-pass top2 fold overlays 8 KB scratch on the
// idle slot. waves_per_eu(2,2): pin 2 waves/SIMD -> 256-VGPR budget
// (1 block/CU; LDS caps at 1 anyway) so nothing spills.
__global__
__attribute__((amdgpu_flat_work_group_size(512, 512)))
__attribute__((amdgpu_waves_per_eu(2, 2)))
void score_kernel(
    const _Float16* __restrict__ A3, const _Float16* __restrict__ B3,
    const float* __restrict__ cnorm,
    float* __restrict__ pv1, int* __restrict__ pi1,
    float* __restrict__ pv2, int* __restrict__ pi2) {
    __shared__ _Float16 smem[73728];    // 144 KiB = 3 slots x 24576 halves

    const int tid = threadIdx.x;
    const int w   = tid >> 6;           // wave 0..7
    const int l   = tid & 63;
    const int wm  = w >> 1;             // 0..3 (row quarter)
    const int wn  = w & 1;              // 0..1 (col half)
    const int m16 = l & 15;
    const int qq  = l >> 4;
    const int x7  = l & 7;
    const int pbase  = blockIdx.x * 256;
    const int nsplit = blockIdx.y;      // 0..15

    // staging: thread -> (row tid>>3, linear chunk tid&7) of a 64-row unit;
    // global source chunk pre-swizzled so LDS[r][c] = G[r][c^(r&7)].
    const int srow = tid >> 3;          // 0..63
    const int sc   = ((tid & 7) ^ (srow & 7)) * 8;        // halves
    const _Float16* gA  = A3 + (size_t)(pbase + srow) * 512 + sc;
    const _Float16* gB0 = B3 + (size_t)(nsplit * 512 + srow) * 512 + sc;

    // read-side bases
    const int rA = wm * 64 + m16;       // A row base (+ mi*16), 0..255
    const int rB = wn * 64 + m16;       // B row base (+ ni*16), 0..127
    const int k0 = (qq ^ x7) * 8;       // ks=0 chunk offset (halves); ks=1 -> ^32

    // stage tile ts (global tile index 0..31) into slot ts%3.
    // A: 4 units of 64 rows; B: 2 units of 64 rows. 6 gload_lds / thread.
#define STAGE_TILE(ts) do {                                                     \
    const int slotb_ = ((ts) % 3) * 24576;                                      \
    const long ko_   = (long)(((ts) & 7) * 64);                                 \
    const long bro_  = (long)(((ts) >> 3) * 128) * 512;                         \
    GLOAD_LDS16(gA + 0 * 32768 + ko_, &smem[slotb_ + 0 * 4096 + w * 512]);      \
    GLOAD_LDS16(gA + 1 * 32768 + ko_, &smem[slotb_ + 1 * 4096 + w * 512]);      \
    GLOAD_LDS16(gA + 2 * 32768 + ko_, &smem[slotb_ + 2 * 4096 + w * 512]);      \
    GLOAD_LDS16(gA + 3 * 32768 + ko_, &smem[slotb_ + 3 * 4096 + w * 512]);      \
    GLOAD_LDS16(gB0 + bro_ + 0 * 32768 + ko_,                                   \
                &smem[slotb_ + 16384 + 0 * 4096 + w * 512]);                    \
    GLOAD_LDS16(gB0 + bro_ + 1 * 32768 + ko_,                                   \
                &smem[slotb_ + 16384 + 1 * 4096 + w * 512]);                    \
} while (0)

    // running per-point top2 across the four 128-code passes (threads 0..255)
    float rv1 = 3.0e38f, rv2 = 3.0e38f;
    int   ri1 = 0x7fffffff, ri2 = 0x7fffffff;

    // ---- prologue: tiles 0 and 1 in flight, wait for tile 0
    STAGE_TILE(0);
    STAGE_TILE(1);
    asm volatile("s_waitcnt vmcnt(6)" ::: "memory");
    __builtin_amdgcn_s_barrier();

#pragma unroll 1
    for (int nt = 0; nt < 4; ++nt) {
        const int kbase = nsplit * 512 + nt * 128;

        f32x4 acc[4][4];
#pragma unroll
        for (int mi = 0; mi < 4; ++mi)
#pragma unroll
            for (int ni = 0; ni < 4; ++ni)
                acc[mi][ni] = (f32x4){0.f, 0.f, 0.f, 0.f};

#pragma unroll 1
        for (int g = 0; g < 8; ++g) {
            const int t_ = nt * 8 + g;
            // stage tile t_+2 (issue loads FIRST so they overlap the MFMAs)
            if (t_ + 2 < 32) STAGE_TILE(t_ + 2);

            // per-ks fragment reads from slot t_%3 (8 live half8, read once)
            const int rb = (t_ % 3) * 24576;
#pragma unroll
            for (int ks = 0; ks < 2; ++ks) {
                const int ko = k0 ^ (ks * 32);
                half8 af[4], bf[4];
#pragma unroll
                for (int mi = 0; mi < 4; ++mi)
                    af[mi] = *(const half8*)&smem[rb + (rA + mi * 16) * 64 + ko];
#pragma unroll
                for (int ni = 0; ni < 4; ++ni)
                    bf[ni] = *(const half8*)&smem[rb + 16384 + (rB + ni * 16) * 64 + ko];

                __builtin_amdgcn_s_setprio(1);
#pragma unroll
                for (int mi = 0; mi < 4; ++mi)
#pragma unroll
                    for (int ni = 0; ni < 4; ++ni)
                        acc[mi][ni] = __builtin_amdgcn_mfma_f32_16x16x32_f16(
                            af[mi], bf[ni], acc[mi][ni], 0, 0, 0);
                __builtin_amdgcn_s_setprio(0);
            }

            // counted waits: ensure tile t_+1 is resident before next iter.
            if (t_ < 30)       asm volatile("s_waitcnt vmcnt(6)" ::: "memory");
            else if (t_ == 30) asm volatile("s_waitcnt vmcnt(0)" ::: "memory");
            __builtin_amdgcn_s_barrier();
        }

        // ---- per-pass fold: scores -> per-lane top2-of-4(ni) -> 16-lane
        // merge -> scratch (overlay on slot (nt*8+7)%3, idle until t_+1 stages)
        {
            const int scrb = ((nt * 8 + 7) % 3) * 24576;
            float* sc1 = (float*)&smem[scrb];
            float* sc2 = sc1 + 512;
            int*   si1 = (int*)(sc2 + 512);
            int*   si2 = si1 + 512;

            const int kb2 = kbase + wn * 64;
            float cn[4];
#pragma unroll
            for (int ni = 0; ni < 4; ++ni) cn[ni] = cnorm[kb2 + ni * 16 + m16];

#pragma unroll
            for (int mi = 0; mi < 4; ++mi) {
#pragma unroll
                for (int r = 0; r < 4; ++r) {
                    float a1 = 3.0e38f, a2 = 3.0e38f;
                    int   b1 = 0x7fffffff, b2 = 0x7fffffff;
#pragma unroll
                    for (int ni = 0; ni < 4; ++ni) {  // k ascending: low k wins ties
                        const float s = fmaf(-2.0f, acc[mi][ni][r], cn[ni]);
                        const int k = kb2 + ni * 16 + m16;
                        if (s < a1) { a2 = a1; b2 = b1; a1 = s; b1 = k; }
                        else if (s < a2) { a2 = s; b2 = k; }
                    }
#pragma unroll
                    for (int m = 1; m < 16; m <<= 1) {
                        const float c1 = __shfl_xor(a1, m, 64);
                        const int   d1 = __shfl_xor(b1, m, 64);
                        const float c2 = __shfl_xor(a2, m, 64);
                        const int   d2 = __shfl_xor(b2, m, 64);
                        top2_merge(a1, b1, a2, b2, c1, d1, c2, d2);
                    }
                    if ((l & 15) == 0) {
                        const int pr = wm * 64 + mi * 16 + qq * 4 + r;  // 0..255
                        sc1[pr * 2 + wn] = a1; si1[pr * 2 + wn] = b1;
                        sc2[pr * 2 + wn] = a2; si2[pr * 2 + wn] = b2;
                    }
                }
            }
            __syncthreads();
            if (tid < 256) {
                float a1 = sc1[tid * 2], a2 = sc2[tid * 2];
                int   b1 = si1[tid * 2], b2 = si2[tid * 2];
                top2_merge(a1, b1, a2, b2, sc1[tid * 2 + 1], si1[tid * 2 + 1],
                           sc2[tid * 2 + 1], si2[tid * 2 + 1]);
                top2_merge(rv1, ri1, rv2, ri2, a1, b1, a2, b2);
            }
            __syncthreads();   // scratch reads done before t_+1 stages over it
        }
    }

    if (tid < 256) {
        const size_t o = (size_t)nsplit * N_PTS + pbase + tid;
        pv1[o] = rv1; pi1[o] = ri1;
        pv2[o] = rv2; pi2[o] = ri2;
    }
#undef STAGE_TILE
}

// ---------------------------------------------------------------- gather
// UNCHANGED from R7 (verified): parallel split merge + fp64 rescore of
// near-ties + fused gather/histogram/loss.
__global__ __launch_bounds__(128) void gather_kernel(
    const float* __restrict__ z_e, const float* __restrict__ cb,
    const float* __restrict__ pv1, const int* __restrict__ pi1,
    const float* __restrict__ pv2, const int* __restrict__ pi2,
    float* __restrict__ out_q, float* __restrict__ out_idx,
    unsigned int* __restrict__ counts, float* __restrict__ psums) {
    const int p = blockIdx.x;
    const int t = threadIdx.x;

    __shared__ float sv1[NSPLIT], sv2[NSPLIT];
    __shared__ int   si1[NSPLIT], si2[NSPLIT];
    if (t < NSPLIT) {
        const size_t o = (size_t)t * N_PTS + p;
        sv1[t] = pv1[o]; si1[t] = pi1[o];
        sv2[t] = pv2[o]; si2[t] = pi2[o];
    }
    __syncthreads();

    float bv = 3.0e38f; int bi = 0x7fffffff;
#pragma unroll
    for (int s = 0; s < NSPLIT; ++s) {
        const float v = sv1[s];
        const int i = si1[s];
        if (v < bv || (v == bv && i < bi)) { bv = v; bi = i; }
    }
    float second = 3.0e38f;
    int cand[8]; int nc = 1; cand[0] = bi;
#pragma unroll
    for (int s = 0; s < NSPLIT; ++s) {
        const float v = sv1[s];
        const int i = si1[s];
        const float w2 = sv2[s];
        const int j = si2[s];
        if (i != bi) {
            if (v < second) second = v;
            if (v <= bv + MARGIN && nc < 8) cand[nc++] = i;
        }
        if (j != bi) {
            if (w2 < second) second = w2;
            if (w2 <= bv + MARGIN && nc < 8) cand[nc++] = j;
        }
    }

    __shared__ double dred[2];
    if (second - bv <= MARGIN && nc > 1) {     // block-uniform condition
        double bestv = 1.0e300; int besti = 0x7fffffff;
        for (int c = 0; c < nc; ++c) {
            const int k = cand[c];
            double part = 0.0;
#pragma unroll
            for (int j = 0; j < 4; ++j) {
                const int d = t * 4 + j;
                const double cv = (double)cb[(size_t)k * DIM + d];
                const double zv = (double)z_e[(size_t)p * DIM + d];
                part += cv * cv - 2.0 * zv * cv;
            }
#pragma unroll
            for (int o = 32; o > 0; o >>= 1) part += __shfl_down(part, o, 64);
            if ((t & 63) == 0) dred[t >> 6] = part;
            __syncthreads();
            const double s = dred[0] + dred[1];
            __syncthreads();
            if (s < bestv || (s == bestv && k < besti)) { bestv = s; besti = k; }
        }
        bi = besti;
    }

    const float4 z = *(const float4*)(z_e + (size_t)p * DIM + t * 4);
    const float4 c = *(const float4*)(cb + (size_t)bi * DIM + t * 4);
    float4 d, o;
    d.x = c.x - z.x; d.y = c.y - z.y; d.z = c.z - z.z; d.w = c.w - z.w;
    o.x = z.x + d.x; o.y = z.y + d.y; o.z = z.z + d.z; o.w = z.w + d.w;
    *(float4*)(out_q + (size_t)p * DIM + t * 4) = o;
    float ls = d.x * d.x + d.y * d.y + d.z * d.z + d.w * d.w;
#pragma unroll
    for (int off = 32; off > 0; off >>= 1) ls += __shfl_down(ls, off, 64);
    __shared__ float red[2];
    if ((t & 63) == 0) red[t >> 6] = ls;
    __syncthreads();
    if (t == 0) {
        psums[p] = red[0] + red[1];
        out_idx[p] = (float)bi;
        atomicAdd(&counts[bi], 1u);
    }
}

// ---------------------------------------------------------------- finalize
__global__ __launch_bounds__(256) void finalize_kernel(
    const unsigned int* __restrict__ counts, const float* __restrict__ psums,
    float* __restrict__ out_scalars) {
    const int t = threadIdx.x;
    float ent = 0.0f;
    for (int b = t; b < K_CODES; b += 256) {
        const float pr = (float)counts[b] * (1.0f / 16384.0f);
        ent += pr * logf(pr + 1e-10f);
    }
    float ss = 0.0f;
    for (int i = t; i < N_PTS; i += 256) ss += psums[i];
#pragma unroll
    for (int off = 32; off > 0; off >>= 1) {
        ent += __shfl_down(ent, off, 64);
        ss += __shfl_down(ss, off, 64);
    }
    __shared__ float re[4], rs[4];
    if ((t & 63) == 0) { re[t >> 6] = ent; rs[t >> 6] = ss; }
    __syncthreads();
    if (t == 0) {
        const float loss = (rs[0] + rs[1] + rs[2] + rs[3]) * (1.0f / NELEM_F);
        out_scalars[0] = loss;
        out_scalars[1] = loss;
        out_scalars[2] = expf(-(re[0] + re[1] + re[2] + re[3]));
    }
}

// ================================================================ fallback
// round-1 pure fp32 path (used only if ws_size < WS_NEED)
#define FB_SPLIT 4
#define FB_KS    (K_CODES / FB_SPLIT)
#define FB_MT    128
#define FB_KT    128
#define FB_DT    32
#define FB_PITCH 36

__global__ __launch_bounds__(256, 2) void fb_dist_argmin_kernel(
    const float* __restrict__ z_e, const float* __restrict__ cb,
    const float* __restrict__ cnorm,
    float* __restrict__ pmin, int* __restrict__ pidx) {
    __shared__ float xs[FB_MT * FB_PITCH];
    __shared__ float cs[FB_KT * FB_PITCH];
    const int tid = threadIdx.x;
    const int tx = tid & 15, ty = tid >> 4;
    const int pbase = blockIdx.x * FB_MT;
    const int kbase0 = blockIdx.y * FB_KS;
    const int scol = (tid & 7) * 4, srow0 = tid >> 3;
    float mn[8], acc[8][8];
    int mi[8];
#pragma unroll
    for (int i = 0; i < 8; ++i) { mn[i] = 3.0e38f; mi[i] = 0; }
    for (int kt = 0; kt < FB_KS / FB_KT; ++kt) {
        const int kbase = kbase0 + kt * FB_KT;
#pragma unroll
        for (int i = 0; i < 8; ++i)
#pragma unroll
            for (int j = 0; j < 8; ++j) acc[i][j] = 0.0f;
        for (int dc = 0; dc < DIM / FB_DT; ++dc) {
            const int dbase = dc * FB_DT;
            __syncthreads();
#pragma unroll
            for (int it = 0; it < 4; ++it) {
                const int row = srow0 + it * 32;
                *(float4*)(xs + row * FB_PITCH + scol) =
                    *(const float4*)(z_e + (size_t)(pbase + row) * DIM + dbase + scol);
                *(float4*)(cs + row * FB_PITCH + scol) =
                    *(const float4*)(cb + (size_t)(kbase + row) * DIM + dbase + scol);
            }
            __syncthreads();
#pragma unroll 2
            for (int dd = 0; dd < FB_DT; dd += 4) {
                float4 xv[8], cv[8];
#pragma unroll
                for (int i = 0; i < 8; ++i)
                    xv[i] = *(const float4*)(xs + (ty + 16 * i) * FB_PITCH + dd);
#pragma unroll
                for (int j = 0; j < 8; ++j)
                    cv[j] = *(const float4*)(cs + (tx + 16 * j) * FB_PITCH + dd);
#pragma unroll
                for (int i = 0; i < 8; ++i)
#pragma unroll
                    for (int j = 0; j < 8; ++j)
                        acc[i][j] += xv[i].x * cv[j].x + xv[i].y * cv[j].y +
                                     xv[i].z * cv[j].z + xv[i].w * cv[j].w;
            }
        }
#pragma unroll
        for (int j = 0; j < 8; ++j) {
            const int k = kbase + tx + 16 * j;
            const float cn = cnorm[k];
#pragma unroll
            for (int i = 0; i < 8; ++i) {
                const float s = cn - 2.0f * acc[i][j];
                if (s < mn[i]) { mn[i] = s; mi[i] = k; }
            }
        }
    }
    float* rmin = xs;
    int* ridx = (int*)cs;
    __syncthreads();
#pragma unroll
    for (int i = 0; i < 8; ++i) {
        const int p = ty + 16 * i;
        rmin[p * 16 + tx] = mn[i];
        ridx[p * 16 + tx] = mi[i];
    }
    __syncthreads();
    if (tid < FB_MT) {
        float best = rmin[tid * 16];
        int bi = ridx[tid * 16];
#pragma unroll
        for (int t = 1; t < 16; ++t) {
            const float v = rmin[tid * 16 + t];
            const int k2 = ridx[tid * 16 + t];
            if (v < best || (v == best && k2 < bi)) { best = v; bi = k2; }
        }
        pmin[(size_t)blockIdx.y * N_PTS + pbase + tid] = best;
        pidx[(size_t)blockIdx.y * N_PTS + pbase + tid] = bi;
    }
}

__global__ __launch_bounds__(128) void fb_gather_kernel(
    const float* __restrict__ z_e, const float* __restrict__ cb,
    const float* __restrict__ pmin, const int* __restrict__ pidx,
    float* __restrict__ out_q, float* __restrict__ out_idx,
    unsigned int* __restrict__ counts, float* __restrict__ psums) {
    const int p = blockIdx.x;
    const int t = threadIdx.x;
    float best = pmin[p];
    int bi = pidx[p];
#pragma unroll
    for (int s = 1; s < FB_SPLIT; ++s) {
        const float v = pmin[(size_t)s * N_PTS + p];
        const int k2 = pidx[(size_t)s * N_PTS + p];
        if (v < best || (v == best && k2 < bi)) { best = v; bi = k2; }
    }
    const float4 z = *(const float4*)(z_e + (size_t)p * DIM + t * 4);
    const float4 c = *(const float4*)(cb + (size_t)bi * DIM + t * 4);
    float4 d, o;
    d.x = c.x - z.x; d.y = c.y - z.y; d.z = c.z - z.z; d.w = c.w - z.w;
    o.x = z.x + d.x; o.y = z.y + d.y; o.z = z.z + d.z; o.w = z.w + d.w;
    *(float4*)(out_q + (size_t)p * DIM + t * 4) = o;
    float ls = d.x * d.x + d.y * d.y + d.z * d.z + d.w * d.w;
#pragma unroll
    for (int off = 32; off > 0; off >>= 1) ls += __shfl_down(ls, off, 64);
    __shared__ float red[2];
    if ((t & 63) == 0) red[t >> 6] = ls;
    __syncthreads();
    if (t == 0) {
        psums[p] = red[0] + red[1];
        out_idx[p] = (float)bi;
        atomicAdd(&counts[bi], 1u);
    }
}

// ================================================================ launch
extern "C" void kernel_launch(void* const* d_in, const int* in_sizes, int n_in,
                              void* d_out, int out_size, void* d_ws, size_t ws_size,
                              hipStream_t stream) {
    const float* z_e = (const float*)d_in[0];
    const float* cb  = (const float*)d_in[1];
    float* out = (float*)d_out;
    char* ws = (char*)d_ws;

    if (ws_size >= WS_NEED) {
        _Float16* A3      = (_Float16*)(ws + OFF_A3);
        _Float16* B3      = (_Float16*)(ws + OFF_B3);
        float* cnorm      = (float*)(ws + OFF_CN);
        float* pv1        = (float*)(ws + OFF_PV1);
        int* pi1          = (int*)(ws + OFF_PI1);
        float* pv2        = (float*)(ws + OFF_PV2);
        int* pi2          = (int*)(ws + OFF_PI2);
        float* psums      = (float*)(ws + OFF_PSUM);
        unsigned int* cnt = (unsigned int*)(ws + OFF_CNT);

        prep_all<<<N_PTS + K_CODES, 128, 0, stream>>>(z_e, cb, A3, B3, cnorm, cnt);
        dim3 g(N_PTS / 256, NSPLIT);                   // 64 x 16 blocks, 512 thr
        score_kernel<<<g, 512, 0, stream>>>(A3, B3, cnorm, pv1, pi1, pv2, pi2);
        gather_kernel<<<N_PTS, 128, 0, stream>>>(z_e, cb, pv1, pi1, pv2, pi2,
                                                 out, out + OUT0_N, cnt, psums);
        finalize_kernel<<<1, 256, 0, stream>>>(cnt, psums, out + OUT0_N + N_PTS);
    } else {
        // round-1 fp32 fallback (<700 KB ws)
        float* cnorm      = (float*)ws;
        float* pmin       = (float*)(ws + 32768);
        int* pidx         = (int*)(ws + 32768 + 262144);
        unsigned int* cnt = (unsigned int*)(ws + 32768 + 2 * 262144);
        float* psums      = (float*)(ws + 32768 + 2 * 262144 + 32768);

        hipMemsetAsync(cnt, 0, 32768, stream);
        cnorm_kernel<<<K_CODES, 128, 0, stream>>>(cb, cnorm);
        dim3 grid1(N_PTS / FB_MT, FB_SPLIT);
        fb_dist_argmin_kernel<<<grid1, 256, 0, stream>>>(z_e, cb, cnorm, pmin, pidx);
        fb_gather_kernel<<<N_PTS, 128, 0, stream>>>(z_e, cb, pmin, pidx,
                                                    out, out + OUT0_N, cnt, psums);
        finalize_kernel<<<1, 256, 0, stream>>>(cnt, psums, out + OUT0_N + N_PTS);
    }
}

// Round 5
// 368.778 us; speedup vs baseline: 2.0664x; 2.0414x over previous
//
#include <hip/hip_runtime.h>

// ---------------------------------------------------------------------------
// VectorQuantizer: N=16384 points x K=8192 codes x D=512 fp32.
// R12: REVERT score GEMM to the harness-verified R7 kernel (224us, 27%
// MfmaUtil, zero spill). R8-R11 (512-thread raw-barrier pipelines) all
// clamped at ~660us with identical profiles (MfmaUtil 8.7%, 30-50MB
// anomalous scratch WRITE_SIZE) regardless of schedule; the compiler
// demotes the working set to scratch in that configuration and no budget
// lever moved VGPR_Count. Dead end documented; banked kernel restored.
// NEW in R12: prep_all rewritten from 24576 blocks x 1-float4-per-thread
// (dispatch/latency-bound) to 1024 blocks x 256 thr grid-stride (8 f4/thr;
// one cb row per wave, same 64-lane shfl cnorm reduce; counts zeroed
// grid-stride). Same arithmetic; cnorm last-ulp diffs are absorbed by the
// MARGIN + fp64-rescore machinery.
// Fallback (small ws): round-1 pure-fp32 VALU kernel (known-correct).
// ---------------------------------------------------------------------------

#define N_PTS   16384
#define DIM     512
#define K_CODES 8192
#define KB      512                   // screening K (hi only)
#define NSPLIT  16                    // code splits (512 codes each)
#define OUT0_N  (N_PTS * DIM)
#define NELEM_F (8388608.0f)
#define MARGIN  1.5e-2f

typedef _Float16 half8 __attribute__((ext_vector_type(8)));
typedef _Float16 f16x4 __attribute__((ext_vector_type(4)));
typedef float    f32x4 __attribute__((ext_vector_type(4)));

// fast-path workspace layout (bytes)
#define SZ_A3    (16384UL * 512 * 2)               // 16.8 MB
#define SZ_B3    (8192UL * 512 * 2)                // 8.4 MB
#define OFF_A3   0UL
#define OFF_B3   (OFF_A3 + SZ_A3)
#define OFF_CN   (OFF_B3 + SZ_B3)                  // cnorm 32 KB
#define OFF_PV1  (OFF_CN + 32768UL)
#define SZ_P     (16UL * 16384 * 4)                // 1 MB each
#define OFF_PI1  (OFF_PV1 + SZ_P)
#define OFF_PV2  (OFF_PI1 + SZ_P)
#define OFF_PI2  (OFF_PV2 + SZ_P)
#define OFF_PSUM (OFF_PI2 + SZ_P)                  // psums 64 KB
#define OFF_CNT  (OFF_PSUM + 65536UL)              // counts 32 KB
#define WS_NEED  (OFF_CNT + 32768UL)

#define GLOAD_LDS16(g, l) \
    __builtin_amdgcn_global_load_lds( \
        (const __attribute__((address_space(1))) unsigned int*)(g), \
        (__attribute__((address_space(3))) unsigned int*)(l), 16, 0, 0)

// ---------------------------------------------------------------- prep (fused)
// R12: grid-stride, 1024 blocks x 256 threads.
//  - counts[0..8191] zeroed grid-stride (stream-ordered before gather)
//  - z_e cast: 2,097,152 float4s, 8 per thread
//  - cb rows: one row per wave (64 lanes x 8 elems); cast + cnorm via the
//    same 64-lane shfl_down reduce as before (lane-local float4x2 first)
__global__ __launch_bounds__(256) void prep_all(const float* __restrict__ z_e,
                                                const float* __restrict__ cb,
                                                _Float16* __restrict__ A3,
                                                _Float16* __restrict__ B3,
                                                float* __restrict__ cnorm,
                                                unsigned int* __restrict__ counts) {
    const int tid   = threadIdx.x;
    const int gid0  = blockIdx.x * 256 + tid;
    const int gsize = gridDim.x * 256;

    for (int i = gid0; i < K_CODES; i += gsize) counts[i] = 0u;

    const long nz4 = (long)N_PTS * DIM / 4;        // 2,097,152
    for (long i = gid0; i < nz4; i += gsize) {
        const float4 v = ((const float4*)z_e)[i];
        f16x4 h;
        h[0] = (_Float16)v.x; h[1] = (_Float16)v.y;
        h[2] = (_Float16)v.z; h[3] = (_Float16)v.w;
        ((f16x4*)A3)[i] = h;
    }

    const int lane   = tid & 63;
    const int wave   = gid0 >> 6;                  // global wave id
    const int nwaves = gsize >> 6;
    for (int r = wave; r < K_CODES; r += nwaves) {
        const float* src = cb + (size_t)r * DIM + lane * 8;
        const float4 v0 = *(const float4*)(src);
        const float4 v1 = *(const float4*)(src + 4);
        f16x4 h0, h1;
        h0[0] = (_Float16)v0.x; h0[1] = (_Float16)v0.y;
        h0[2] = (_Float16)v0.z; h0[3] = (_Float16)v0.w;
        h1[0] = (_Float16)v1.x; h1[1] = (_Float16)v1.y;
        h1[2] = (_Float16)v1.z; h1[3] = (_Float16)v1.w;
        _Float16* dst = B3 + (size_t)r * 512 + lane * 8;
        *(f16x4*)(dst)     = h0;
        *(f16x4*)(dst + 4) = h1;
        float s = v0.x * v0.x + v0.y * v0.y + v0.z * v0.z + v0.w * v0.w
                + v1.x * v1.x + v1.y * v1.y + v1.z * v1.z + v1.w * v1.w;
#pragma unroll
        for (int o = 32; o > 0; o >>= 1) s += __shfl_down(s, o, 64);
        if (lane == 0) cnorm[r] = s;
    }
}

// ---------------------------------------------------------------- cnorm (fallback)
__global__ __launch_bounds__(128) void cnorm_kernel(const float* __restrict__ cb,
                                                    float* __restrict__ cnorm) {
    const int k = blockIdx.x;
    const int t = threadIdx.x;
    const float4 v = *(const float4*)(cb + (size_t)k * DIM + t * 4);
    float s = v.x * v.x + v.y * v.y + v.z * v.z + v.w * v.w;
#pragma unroll
    for (int o = 32; o > 0; o >>= 1) s += __shfl_down(s, o, 64);
    __shared__ float red[2];
    if ((t & 63) == 0) red[t >> 6] = s;
    __syncthreads();
    if (t == 0) cnorm[k] = red[0] + red[1];
}

// ---------------------------------------------------------------- score GEMM
// [VERIFIED R7 KERNEL — restored verbatim] 128x128 tile, BK=64,
// global_load_lds w=16, 4 waves 2x2, each wave 64x64 via 4x4 of 16x16x32
// f16 MFMA. Block loops 4 code tiles (one 512-code split) over K'=512.
// LDS XOR-swizzled at 16B-chunk granularity (conflicts -> 0). Top-2
// (val, packed idx) per point-slot; inter-wave LDS merge epilogue.
__global__ __launch_bounds__(256, 3) void score_kernel(
    const _Float16* __restrict__ A3, const _Float16* __restrict__ B3,
    const float* __restrict__ cnorm,
    float* __restrict__ pv1, int* __restrict__ pi1,
    float* __restrict__ pv2, int* __restrict__ pi2) {
    __shared__ _Float16 As[128 * 64];   // 16 KB
    __shared__ _Float16 Bs[128 * 64];   // 16 KB
    __shared__ float mv1[128][2], mv2[128][2];
    __shared__ int   mj1[128][2], mj2[128][2];

    const int tid = threadIdx.x;
    const int w = tid >> 6;             // wave 0..3
    const int l = tid & 63;
    const int pbase = blockIdx.x * 128;
    const int nsplit = blockIdx.y;      // 0..15
    const int wmb = (w >> 1) * 64;      // wave m offset
    const int wnb = (w & 1) * 64;       // wave n offset
    const int srow = w * 8 + (l >> 3);  // staging row (+ it*32)
    const int scolh = (((l & 7) ^ ((l >> 3) & 7)) * 8);   // swizzled src col

    const _Float16* aB[4];
    const _Float16* bR[4];
#pragma unroll
    for (int it = 0; it < 4; ++it) {
        aB[it] = A3 + (long)(pbase + it * 32 + srow) * 512 + scolh;
        bR[it] = B3 + (long)(it * 32 + srow) * 512 + scolh;
    }

    const int q = l >> 4, x7 = l & 7, m16 = l & 15;
    const int koff0 = ((q ^ x7) * 8);          // ks=0 chunk offset (halves)
    const int rowAf = (wmb + m16) * 64;        // + mi*1024
    const int rowBf = (wnb + m16) * 64;        // + ni*1024

    float v1[16], v2[16];
    int i12[16];                               // (i1<<16) | i2, codes < 8192
#pragma unroll
    for (int s = 0; s < 16; ++s) { v1[s] = 3.0e38f; v2[s] = 3.0e38f; i12[s] = 0; }

#pragma unroll 1
    for (int nt = 0; nt < 4; ++nt) {
        const int kbase = nsplit * 512 + nt * 128;   // code row base
        const long bOff = (long)kbase * 512;
        f32x4 acc[4][4];
#pragma unroll
        for (int mi = 0; mi < 4; ++mi)
#pragma unroll
            for (int ni = 0; ni < 4; ++ni)
                acc[mi][ni] = (f32x4){0.f, 0.f, 0.f, 0.f};

#pragma unroll 1
        for (int kt = 0; kt < KB / 64; ++kt) {       // 8 iterations
            const long ka = (long)kt * 64;
            __syncthreads();                          // LDS reuse guard
#pragma unroll
            for (int it = 0; it < 4; ++it)
                GLOAD_LDS16(aB[it] + ka, &As[it * 2048 + w * 512]);
#pragma unroll
            for (int it = 0; it < 4; ++it)
                GLOAD_LDS16(bR[it] + bOff + ka, &Bs[it * 2048 + w * 512]);
            __syncthreads();                          // drains vmcnt for glds
#pragma unroll
            for (int ks = 0; ks < 2; ++ks) {
                const int ko = koff0 ^ (ks * 32);
                half8 af[4], bf[4];
#pragma unroll
                for (int mi = 0; mi < 4; ++mi)
                    af[mi] = *(half8*)&As[rowAf + mi * 1024 + ko];
#pragma unroll
                for (int ni = 0; ni < 4; ++ni)
                    bf[ni] = *(half8*)&Bs[rowBf + ni * 1024 + ko];
#pragma unroll
                for (int mi = 0; mi < 4; ++mi)
#pragma unroll
                    for (int ni = 0; ni < 4; ++ni)
                        acc[mi][ni] = __builtin_amdgcn_mfma_f32_16x16x32_f16(
                            af[mi], bf[ni], acc[mi][ni], 0, 0, 0);
            }
        }
        // fold this tile's scores into per-lane top2
#pragma unroll
        for (int ni = 0; ni < 4; ++ni) {
            const int k = kbase + wnb + ni * 16 + m16;
            const float cn = cnorm[k];
#pragma unroll
            for (int mi = 0; mi < 4; ++mi)
#pragma unroll
                for (int r = 0; r < 4; ++r) {
                    const float s = fmaf(-2.0f, acc[mi][ni][r], cn);
                    const int slot = mi * 4 + r;
                    if (s < v1[slot]) {               // strict <: lowest k wins
                        v2[slot] = v1[slot];
                        i12[slot] = (k << 16) | (i12[slot] >> 16);
                        v1[slot] = s;
                    } else if (s < v2[slot]) {
                        v2[slot] = s;
                        i12[slot] = (i12[slot] & 0xffff0000) | k;
                    }
                }
        }
    }

    // cross-lane top2 reduce over the 16 lanes sharing each point row,
    // deposit per (point, column-half) into LDS
#pragma unroll
    for (int slot = 0; slot < 16; ++slot) {
        float a1 = v1[slot], a2 = v2[slot];
        int b1 = i12[slot] >> 16, b2 = i12[slot] & 0xffff;
#pragma unroll
        for (int m = 1; m < 16; m <<= 1) {
            const float c1 = __shfl_xor(a1, m, 64);
            const int   d1 = __shfl_xor(b1, m, 64);
            const float c2 = __shfl_xor(a2, m, 64);
            const int   d2 = __shfl_xor(b2, m, 64);
            if (c1 < a1 || (c1 == a1 && d1 < b1)) {
                if (a1 < c2 || (a1 == c2 && b1 < d2)) { a2 = a1; b2 = b1; }
                else { a2 = c2; b2 = d2; }
                a1 = c1; b1 = d1;
            } else {
                if (c1 < a2 || (c1 == a2 && d1 < b2)) { a2 = c1; b2 = d1; }
            }
        }
        if ((l & 15) == 0) {
            const int sm = slot >> 2, sr = slot & 3;
            const int pr = wmb + sm * 16 + (l >> 4) * 4 + sr;  // 0..127
            const int h = w & 1;                               // column half
            mv1[pr][h] = a1; mj1[pr][h] = b1;
            mv2[pr][h] = a2; mj2[pr][h] = b2;
        }
    }
    __syncthreads();
    // merge the two column-halves per point; single global write
    if (tid < 128) {
        float a1 = mv1[tid][0], a2 = mv2[tid][0];
        int b1 = mj1[tid][0], b2 = mj2[tid][0];
        const float c1 = mv1[tid][1], c2 = mv2[tid][1];
        const int   d1 = mj1[tid][1], d2 = mj2[tid][1];
        if (c1 < a1 || (c1 == a1 && d1 < b1)) {
            if (a1 < c2 || (a1 == c2 && b1 < d2)) { a2 = a1; b2 = b1; }
            else { a2 = c2; b2 = d2; }
            a1 = c1; b1 = d1;
        } else {
            if (c1 < a2 || (c1 == a2 && d1 < b2)) { a2 = c1; b2 = d1; }
        }
        const size_t o = (size_t)nsplit * N_PTS + pbase + tid;
        pv1[o] = a1; pi1[o] = b1; pv2[o] = a2; pi2[o] = b2;
    }
}

// ---------------------------------------------------------------- gather
// UNCHANGED (verified): parallel split merge + fp64 rescore of near-ties +
// fused gather/histogram/loss.
__global__ __launch_bounds__(128) void gather_kernel(
    const float* __restrict__ z_e, const float* __restrict__ cb,
    const float* __restrict__ pv1, const int* __restrict__ pi1,
    const float* __restrict__ pv2, const int* __restrict__ pi2,
    float* __restrict__ out_q, float* __restrict__ out_idx,
    unsigned int* __restrict__ counts, float* __restrict__ psums) {
    const int p = blockIdx.x;
    const int t = threadIdx.x;

    __shared__ float sv1[NSPLIT], sv2[NSPLIT];
    __shared__ int   si1[NSPLIT], si2[NSPLIT];
    if (t < NSPLIT) {
        const size_t o = (size_t)t * N_PTS + p;
        sv1[t] = pv1[o]; si1[t] = pi1[o];
        sv2[t] = pv2[o]; si2[t] = pi2[o];
    }
    __syncthreads();

    float bv = 3.0e38f; int bi = 0x7fffffff;
#pragma unroll
    for (int s = 0; s < NSPLIT; ++s) {
        const float v = sv1[s];
        const int i = si1[s];
        if (v < bv || (v == bv && i < bi)) { bv = v; bi = i; }
    }
    float second = 3.0e38f;
    int cand[8]; int nc = 1; cand[0] = bi;
#pragma unroll
    for (int s = 0; s < NSPLIT; ++s) {
        const float v = sv1[s];
        const int i = si1[s];
        const float w2 = sv2[s];
        const int j = si2[s];
        if (i != bi) {
            if (v < second) second = v;
            if (v <= bv + MARGIN && nc < 8) cand[nc++] = i;
        }
        if (j != bi) {
            if (w2 < second) second = w2;
            if (w2 <= bv + MARGIN && nc < 8) cand[nc++] = j;
        }
    }

    __shared__ double dred[2];
    if (second - bv <= MARGIN && nc > 1) {     // block-uniform condition
        double bestv = 1.0e300; int besti = 0x7fffffff;
        for (int c = 0; c < nc; ++c) {
            const int k = cand[c];
            double part = 0.0;
#pragma unroll
            for (int j = 0; j < 4; ++j) {
                const int d = t * 4 + j;
                const double cv = (double)cb[(size_t)k * DIM + d];
                const double zv = (double)z_e[(size_t)p * DIM + d];
                part += cv * cv - 2.0 * zv * cv;
            }
#pragma unroll
            for (int o = 32; o > 0; o >>= 1) part += __shfl_down(part, o, 64);
            if ((t & 63) == 0) dred[t >> 6] = part;
            __syncthreads();
            const double s = dred[0] + dred[1];
            __syncthreads();
            if (s < bestv || (s == bestv && k < besti)) { bestv = s; besti = k; }
        }
        bi = besti;
    }

    const float4 z = *(const float4*)(z_e + (size_t)p * DIM + t * 4);
    const float4 c = *(const float4*)(cb + (size_t)bi * DIM + t * 4);
    float4 d, o;
    d.x = c.x - z.x; d.y = c.y - z.y; d.z = c.z - z.z; d.w = c.w - z.w;
    o.x = z.x + d.x; o.y = z.y + d.y; o.z = z.z + d.z; o.w = z.w + d.w;
    *(float4*)(out_q + (size_t)p * DIM + t * 4) = o;
    float ls = d.x * d.x + d.y * d.y + d.z * d.z + d.w * d.w;
#pragma unroll
    for (int off = 32; off > 0; off >>= 1) ls += __shfl_down(ls, off, 64);
    __shared__ float red[2];
    if ((t & 63) == 0) red[t >> 6] = ls;
    __syncthreads();
    if (t == 0) {
        psums[p] = red[0] + red[1];
        out_idx[p] = (float)bi;
        atomicAdd(&counts[bi], 1u);
    }
}

// ---------------------------------------------------------------- finalize
__global__ __launch_bounds__(256) void finalize_kernel(
    const unsigned int* __restrict__ counts, const float* __restrict__ psums,
    float* __restrict__ out_scalars) {
    const int t = threadIdx.x;
    float ent = 0.0f;
    for (int b = t; b < K_CODES; b += 256) {
        const float pr = (float)counts[b] * (1.0f / 16384.0f);
        ent += pr * logf(pr + 1e-10f);
    }
    float ss = 0.0f;
    for (int i = t; i < N_PTS; i += 256) ss += psums[i];
#pragma unroll
    for (int off = 32; off > 0; off >>= 1) {
        ent += __shfl_down(ent, off, 64);
        ss += __shfl_down(ss, off, 64);
    }
    __shared__ float re[4], rs[4];
    if ((t & 63) == 0) { re[t >> 6] = ent; rs[t >> 6] = ss; }
    __syncthreads();
    if (t == 0) {
        const float loss = (rs[0] + rs[1] + rs[2] + rs[3]) * (1.0f / NELEM_F);
        out_scalars[0] = loss;
        out_scalars[1] = loss;
        out_scalars[2] = expf(-(re[0] + re[1] + re[2] + re[3]));
    }
}

// ================================================================ fallback
// round-1 pure fp32 path (used only if ws_size < WS_NEED)
#define FB_SPLIT 4
#define FB_KS    (K_CODES / FB_SPLIT)
#define FB_MT    128
#define FB_KT    128
#define FB_DT    32
#define FB_PITCH 36

__global__ __launch_bounds__(256, 2) void fb_dist_argmin_kernel(
    const float* __restrict__ z_e, const float* __restrict__ cb,
    const float* __restrict__ cnorm,
    float* __restrict__ pmin, int* __restrict__ pidx) {
    __shared__ float xs[FB_MT * FB_PITCH];
    __shared__ float cs[FB_KT * FB_PITCH];
    const int tid = threadIdx.x;
    const int tx = tid & 15, ty = tid >> 4;
    const int pbase = blockIdx.x * FB_MT;
    const int kbase0 = blockIdx.y * FB_KS;
    const int scol = (tid & 7) * 4, srow0 = tid >> 3;
    float mn[8], acc[8][8];
    int mi[8];
#pragma unroll
    for (int i = 0; i < 8; ++i) { mn[i] = 3.0e38f; mi[i] = 0; }
    for (int kt = 0; kt < FB_KS / FB_KT; ++kt) {
        const int kbase = kbase0 + kt * FB_KT;
#pragma unroll
        for (int i = 0; i < 8; ++i)
#pragma unroll
            for (int j = 0; j < 8; ++j) acc[i][j] = 0.0f;
        for (int dc = 0; dc < DIM / FB_DT; ++dc) {
            const int dbase = dc * FB_DT;
            __syncthreads();
#pragma unroll
            for (int it = 0; it < 4; ++it) {
                const int row = srow0 + it * 32;
                *(float4*)(xs + row * FB_PITCH + scol) =
                    *(const float4*)(z_e + (size_t)(pbase + row) * DIM + dbase + scol);
                *(float4*)(cs + row * FB_PITCH + scol) =
                    *(const float4*)(cb + (size_t)(kbase + row) * DIM + dbase + scol);
            }
            __syncthreads();
#pragma unroll 2
            for (int dd = 0; dd < FB_DT; dd += 4) {
                float4 xv[8], cv[8];
#pragma unroll
                for (int i = 0; i < 8; ++i)
                    xv[i] = *(const float4*)(xs + (ty + 16 * i) * FB_PITCH + dd);
#pragma unroll
                for (int j = 0; j < 8; ++j)
                    cv[j] = *(const float4*)(cs + (tx + 16 * j) * FB_PITCH + dd);
#pragma unroll
                for (int i = 0; i < 8; ++i)
#pragma unroll
                    for (int j = 0; j < 8; ++j)
                        acc[i][j] += xv[i].x * cv[j].x + xv[i].y * cv[j].y +
                                     xv[i].z * cv[j].z + xv[i].w * cv[j].w;
            }
        }
#pragma unroll
        for (int j = 0; j < 8; ++j) {
            const int k = kbase + tx + 16 * j;
            const float cn = cnorm[k];
#pragma unroll
            for (int i = 0; i < 8; ++i) {
                const float s = cn - 2.0f * acc[i][j];
                if (s < mn[i]) { mn[i] = s; mi[i] = k; }
            }
        }
    }
    float* rmin = xs;
    int* ridx = (int*)cs;
    __syncthreads();
#pragma unroll
    for (int i = 0; i < 8; ++i) {
        const int p = ty + 16 * i;
        rmin[p * 16 + tx] = mn[i];
        ridx[p * 16 + tx] = mi[i];
    }
    __syncthreads();
    if (tid < FB_MT) {
        float best = rmin[tid * 16];
        int bi = ridx[tid * 16];
#pragma unroll
        for (int t = 1; t < 16; ++t) {
            const float v = rmin[tid * 16 + t];
            const int k2 = ridx[tid * 16 + t];
            if (v < best || (v == best && k2 < bi)) { best = v; bi = k2; }
        }
        pmin[(size_t)blockIdx.y * N_PTS + pbase + tid] = best;
        pidx[(size_t)blockIdx.y * N_PTS + pbase + tid] = bi;
    }
}

__global__ __launch_bounds__(128) void fb_gather_kernel(
    const float* __restrict__ z_e, const float* __restrict__ cb,
    const float* __restrict__ pmin, const int* __restrict__ pidx,
    float* __restrict__ out_q, float* __restrict__ out_idx,
    unsigned int* __restrict__ counts, float* __restrict__ psums) {
    const int p = blockIdx.x;
    const int t = threadIdx.x;
    float best = pmin[p];
    int bi = pidx[p];
#pragma unroll
    for (int s = 1; s < FB_SPLIT; ++s) {
        const float v = pmin[(size_t)s * N_PTS + p];
        const int k2 = pidx[(size_t)s * N_PTS + p];
        if (v < best || (v == best && k2 < bi)) { best = v; bi = k2; }
    }
    const float4 z = *(const float4*)(z_e + (size_t)p * DIM + t * 4);
    const float4 c = *(const float4*)(cb + (size_t)bi * DIM + t * 4);
    float4 d, o;
    d.x = c.x - z.x; d.y = c.y - z.y; d.z = c.z - z.z; d.w = c.w - z.w;
    o.x = z.x + d.x; o.y = z.y + d.y; o.z = z.z + d.z; o.w = z.w + d.w;
    *(float4*)(out_q + (size_t)p * DIM + t * 4) = o;
    float ls = d.x * d.x + d.y * d.y + d.z * d.z + d.w * d.w;
#pragma unroll
    for (int off = 32; off > 0; off >>= 1) ls += __shfl_down(ls, off, 64);
    __shared__ float red[2];
    if ((t & 63) == 0) red[t >> 6] = ls;
    __syncthreads();
    if (t == 0) {
        psums[p] = red[0] + red[1];
        out_idx[p] = (float)bi;
        atomicAdd(&counts[bi], 1u);
    }
}

// ================================================================ launch
extern "C" void kernel_launch(void* const* d_in, const int* in_sizes, int n_in,
                              void* d_out, int out_size, void* d_ws, size_t ws_size,
                              hipStream_t stream) {
    const float* z_e = (const float*)d_in[0];
    const float* cb  = (const float*)d_in[1];
    float* out = (float*)d_out;
    char* ws = (char*)d_ws;

    if (ws_size >= WS_NEED) {
        _Float16* A3      = (_Float16*)(ws + OFF_A3);
        _Float16* B3      = (_Float16*)(ws + OFF_B3);
        float* cnorm      = (float*)(ws + OFF_CN);
        float* pv1        = (float*)(ws + OFF_PV1);
        int* pi1          = (int*)(ws + OFF_PI1);
        float* pv2        = (float*)(ws + OFF_PV2);
        int* pi2          = (int*)(ws + OFF_PI2);
        float* psums      = (float*)(ws + OFF_PSUM);
        unsigned int* cnt = (unsigned int*)(ws + OFF_CNT);

        prep_all<<<1024, 256, 0, stream>>>(z_e, cb, A3, B3, cnorm, cnt);
        dim3 g(N_PTS / 128, NSPLIT);                   // 128 x 16 blocks
        score_kernel<<<g, 256, 0, stream>>>(A3, B3, cnorm, pv1, pi1, pv2, pi2);
        gather_kernel<<<N_PTS, 128, 0, stream>>>(z_e, cb, pv1, pi1, pv2, pi2,
                                                 out, out + OUT0_N, cnt, psums);
        finalize_kernel<<<1, 256, 0, stream>>>(cnt, psums, out + OUT0_N + N_PTS);
    } else {
        // round-1 fp32 fallback (<700 KB ws)
        float* cnorm      = (float*)ws;
        float* pmin       = (float*)(ws + 32768);
        int* pidx         = (int*)(ws + 32768 + 262144);
        unsigned int* cnt = (unsigned int*)(ws + 32768 + 2 * 262144);
        float* psums      = (float*)(ws + 32768 + 2 * 262144 + 32768);

        hipMemsetAsync(cnt, 0, 32768, stream);
        cnorm_kernel<<<K_CODES, 128, 0, stream>>>(cb, cnorm);
        dim3 grid1(N_PTS / FB_MT, FB_SPLIT);
        fb_dist_argmin_kernel<<<grid1, 256, 0, stream>>>(z_e, cb, cnorm, pmin, pidx);
        fb_gather_kernel<<<N_PTS, 128, 0, stream>>>(z_e, cb, pmin, pidx,
                                                    out, out + OUT0_N, cnt, psums);
        finalize_kernel<<<1, 256, 0, stream>>>(cnt, psums, out + OUT0_N + N_PTS);
    }
}

// Round 8
// 349.202 us; speedup vs baseline: 2.1822x; 1.0561x over previous
//
#include <hip/hip_runtime.h>

// ---------------------------------------------------------------------------
// VectorQuantizer: N=16384 points x K=8192 codes x D=512 fp32.
// R15: score GEMM = R12-verified kernel VERBATIM (222us, absmax 0). R13/R14's
// stage-ahead reorder FAILED correctness (idx absmax 7751) — reverted and
// abandoned. NEW: gather rewritten wave-per-point (4 points per 256-thr
// block, grid 4096): split-merge via __shfl broadcasts (same s=0..15 scan
// order -> same comparator semantics), wave-uniform fp64 rescore with
// in-wave shfl reduce, no LDS/no barriers in the common path. Old gather
// was ~120us for ~22us of ideal traffic (1 point/block, serial LDS scan).
// prep = R12 grid-stride version (verified). Fallback path unchanged.
// ---------------------------------------------------------------------------

#define N_PTS   16384
#define DIM     512
#define K_CODES 8192
#define KB      512                   // screening K (hi only)
#define NSPLIT  16                    // code splits (512 codes each)
#define OUT0_N  (N_PTS * DIM)
#define NELEM_F (8388608.0f)
#define MARGIN  1.5e-2f

typedef _Float16 half8 __attribute__((ext_vector_type(8)));
typedef _Float16 f16x4 __attribute__((ext_vector_type(4)));
typedef float    f32x4 __attribute__((ext_vector_type(4)));

// fast-path workspace layout (bytes)
#define SZ_A3    (16384UL * 512 * 2)               // 16.8 MB
#define SZ_B3    (8192UL * 512 * 2)                // 8.4 MB
#define OFF_A3   0UL
#define OFF_B3   (OFF_A3 + SZ_A3)
#define OFF_CN   (OFF_B3 + SZ_B3)                  // cnorm 32 KB
#define OFF_PV1  (OFF_CN + 32768UL)
#define SZ_P     (16UL * 16384 * 4)                // 1 MB each
#define OFF_PI1  (OFF_PV1 + SZ_P)
#define OFF_PV2  (OFF_PI1 + SZ_P)
#define OFF_PI2  (OFF_PV2 + SZ_P)
#define OFF_PSUM (OFF_PI2 + SZ_P)                  // psums 64 KB
#define OFF_CNT  (OFF_PSUM + 65536UL)              // counts 32 KB
#define WS_NEED  (OFF_CNT + 32768UL)

#define GLOAD_LDS16(g, l) \
    __builtin_amdgcn_global_load_lds( \
        (const __attribute__((address_space(1))) unsigned int*)(g), \
        (__attribute__((address_space(3))) unsigned int*)(l), 16, 0, 0)

// ---------------------------------------------------------------- prep (fused)
// R12 version (verified): grid-stride, 1024 blocks x 256 threads.
__global__ __launch_bounds__(256) void prep_all(const float* __restrict__ z_e,
                                                const float* __restrict__ cb,
                                                _Float16* __restrict__ A3,
                                                _Float16* __restrict__ B3,
                                                float* __restrict__ cnorm,
                                                unsigned int* __restrict__ counts) {
    const int tid   = threadIdx.x;
    const int gid0  = blockIdx.x * 256 + tid;
    const int gsize = gridDim.x * 256;

    for (int i = gid0; i < K_CODES; i += gsize) counts[i] = 0u;

    const long nz4 = (long)N_PTS * DIM / 4;        // 2,097,152
    for (long i = gid0; i < nz4; i += gsize) {
        const float4 v = ((const float4*)z_e)[i];
        f16x4 h;
        h[0] = (_Float16)v.x; h[1] = (_Float16)v.y;
        h[2] = (_Float16)v.z; h[3] = (_Float16)v.w;
        ((f16x4*)A3)[i] = h;
    }

    const int lane   = tid & 63;
    const int wave   = gid0 >> 6;                  // global wave id
    const int nwaves = gsize >> 6;
    for (int r = wave; r < K_CODES; r += nwaves) {
        const float* src = cb + (size_t)r * DIM + lane * 8;
        const float4 v0 = *(const float4*)(src);
        const float4 v1 = *(const float4*)(src + 4);
        f16x4 h0, h1;
        h0[0] = (_Float16)v0.x; h0[1] = (_Float16)v0.y;
        h0[2] = (_Float16)v0.z; h0[3] = (_Float16)v0.w;
        h1[0] = (_Float16)v1.x; h1[1] = (_Float16)v1.y;
        h1[2] = (_Float16)v1.z; h1[3] = (_Float16)v1.w;
        _Float16* dst = B3 + (size_t)r * 512 + lane * 8;
        *(f16x4*)(dst)     = h0;
        *(f16x4*)(dst + 4) = h1;
        float s = v0.x * v0.x + v0.y * v0.y + v0.z * v0.z + v0.w * v0.w
                + v1.x * v1.x + v1.y * v1.y + v1.z * v1.z + v1.w * v1.w;
#pragma unroll
        for (int o = 32; o > 0; o >>= 1) s += __shfl_down(s, o, 64);
        if (lane == 0) cnorm[r] = s;
    }
}

// ---------------------------------------------------------------- cnorm (fallback)
__global__ __launch_bounds__(128) void cnorm_kernel(const float* __restrict__ cb,
                                                    float* __restrict__ cnorm) {
    const int k = blockIdx.x;
    const int t = threadIdx.x;
    const float4 v = *(const float4*)(cb + (size_t)k * DIM + t * 4);
    float s = v.x * v.x + v.y * v.y + v.z * v.z + v.w * v.w;
#pragma unroll
    for (int o = 32; o > 0; o >>= 1) s += __shfl_down(s, o, 64);
    __shared__ float red[2];
    if ((t & 63) == 0) red[t >> 6] = s;
    __syncthreads();
    if (t == 0) cnorm[k] = red[0] + red[1];
}

// ---------------------------------------------------------------- score GEMM
// [VERIFIED R7/R12 KERNEL — verbatim] 128x128 tile, BK=64, global_load_lds
// w=16, 4 waves 2x2, each wave 64x64 via 4x4 of 16x16x32 f16 MFMA. Block
// loops 4 code tiles (one 512-code split) over K'=512. LDS XOR-swizzled at
// 16B-chunk granularity (conflicts -> 0). Top-2 (val, packed idx) per
// point-slot; inter-wave LDS merge epilogue.
__global__ __launch_bounds__(256, 3) void score_kernel(
    const _Float16* __restrict__ A3, const _Float16* __restrict__ B3,
    const float* __restrict__ cnorm,
    float* __restrict__ pv1, int* __restrict__ pi1,
    float* __restrict__ pv2, int* __restrict__ pi2) {
    __shared__ _Float16 As[128 * 64];   // 16 KB
    __shared__ _Float16 Bs[128 * 64];   // 16 KB
    __shared__ float mv1[128][2], mv2[128][2];
    __shared__ int   mj1[128][2], mj2[128][2];

    const int tid = threadIdx.x;
    const int w = tid >> 6;             // wave 0..3
    const int l = tid & 63;
    const int pbase = blockIdx.x * 128;
    const int nsplit = blockIdx.y;      // 0..15
    const int wmb = (w >> 1) * 64;      // wave m offset
    const int wnb = (w & 1) * 64;       // wave n offset
    const int srow = w * 8 + (l >> 3);  // staging row (+ it*32)
    const int scolh = (((l & 7) ^ ((l >> 3) & 7)) * 8);   // swizzled src col

    const _Float16* aB[4];
    const _Float16* bR[4];
#pragma unroll
    for (int it = 0; it < 4; ++it) {
        aB[it] = A3 + (long)(pbase + it * 32 + srow) * 512 + scolh;
        bR[it] = B3 + (long)(it * 32 + srow) * 512 + scolh;
    }

    const int q = l >> 4, x7 = l & 7, m16 = l & 15;
    const int koff0 = ((q ^ x7) * 8);          // ks=0 chunk offset (halves)
    const int rowAf = (wmb + m16) * 64;        // + mi*1024
    const int rowBf = (wnb + m16) * 64;        // + ni*1024

    float v1[16], v2[16];
    int i12[16];                               // (i1<<16) | i2, codes < 8192
#pragma unroll
    for (int s = 0; s < 16; ++s) { v1[s] = 3.0e38f; v2[s] = 3.0e38f; i12[s] = 0; }

#pragma unroll 1
    for (int nt = 0; nt < 4; ++nt) {
        const int kbase = nsplit * 512 + nt * 128;   // code row base
        const long bOff = (long)kbase * 512;
        f32x4 acc[4][4];
#pragma unroll
        for (int mi = 0; mi < 4; ++mi)
#pragma unroll
            for (int ni = 0; ni < 4; ++ni)
                acc[mi][ni] = (f32x4){0.f, 0.f, 0.f, 0.f};

#pragma unroll 1
        for (int kt = 0; kt < KB / 64; ++kt) {       // 8 iterations
            const long ka = (long)kt * 64;
            __syncthreads();                          // LDS reuse guard
#pragma unroll
            for (int it = 0; it < 4; ++it)
                GLOAD_LDS16(aB[it] + ka, &As[it * 2048 + w * 512]);
#pragma unroll
            for (int it = 0; it < 4; ++it)
                GLOAD_LDS16(bR[it] + bOff + ka, &Bs[it * 2048 + w * 512]);
            __syncthreads();                          // drains vmcnt for glds
#pragma unroll
            for (int ks = 0; ks < 2; ++ks) {
                const int ko = koff0 ^ (ks * 32);
                half8 af[4], bf[4];
#pragma unroll
                for (int mi = 0; mi < 4; ++mi)
                    af[mi] = *(half8*)&As[rowAf + mi * 1024 + ko];
#pragma unroll
                for (int ni = 0; ni < 4; ++ni)
                    bf[ni] = *(half8*)&Bs[rowBf + ni * 1024 + ko];
#pragma unroll
                for (int mi = 0; mi < 4; ++mi)
#pragma unroll
                    for (int ni = 0; ni < 4; ++ni)
                        acc[mi][ni] = __builtin_amdgcn_mfma_f32_16x16x32_f16(
                            af[mi], bf[ni], acc[mi][ni], 0, 0, 0);
            }
        }
        // fold this tile's scores into per-lane top2
#pragma unroll
        for (int ni = 0; ni < 4; ++ni) {
            const int k = kbase + wnb + ni * 16 + m16;
            const float cn = cnorm[k];
#pragma unroll
            for (int mi = 0; mi < 4; ++mi)
#pragma unroll
                for (int r = 0; r < 4; ++r) {
                    const float s = fmaf(-2.0f, acc[mi][ni][r], cn);
                    const int slot = mi * 4 + r;
                    if (s < v1[slot]) {               // strict <: lowest k wins
                        v2[slot] = v1[slot];
                        i12[slot] = (k << 16) | (i12[slot] >> 16);
                        v1[slot] = s;
                    } else if (s < v2[slot]) {
                        v2[slot] = s;
                        i12[slot] = (i12[slot] & 0xffff0000) | k;
                    }
                }
        }
    }

    // cross-lane top2 reduce over the 16 lanes sharing each point row,
    // deposit per (point, column-half) into LDS
#pragma unroll
    for (int slot = 0; slot < 16; ++slot) {
        float a1 = v1[slot], a2 = v2[slot];
        int b1 = i12[slot] >> 16, b2 = i12[slot] & 0xffff;
#pragma unroll
        for (int m = 1; m < 16; m <<= 1) {
            const float c1 = __shfl_xor(a1, m, 64);
            const int   d1 = __shfl_xor(b1, m, 64);
            const float c2 = __shfl_xor(a2, m, 64);
            const int   d2 = __shfl_xor(b2, m, 64);
            if (c1 < a1 || (c1 == a1 && d1 < b1)) {
                if (a1 < c2 || (a1 == c2 && b1 < d2)) { a2 = a1; b2 = b1; }
                else { a2 = c2; b2 = d2; }
                a1 = c1; b1 = d1;
            } else {
                if (c1 < a2 || (c1 == a2 && d1 < b2)) { a2 = c1; b2 = d1; }
            }
        }
        if ((l & 15) == 0) {
            const int sm = slot >> 2, sr = slot & 3;
            const int pr = wmb + sm * 16 + (l >> 4) * 4 + sr;  // 0..127
            const int h = w & 1;                               // column half
            mv1[pr][h] = a1; mj1[pr][h] = b1;
            mv2[pr][h] = a2; mj2[pr][h] = b2;
        }
    }
    __syncthreads();
    // merge the two column-halves per point; single global write
    if (tid < 128) {
        float a1 = mv1[tid][0], a2 = mv2[tid][0];
        int b1 = mj1[tid][0], b2 = mj2[tid][0];
        const float c1 = mv1[tid][1], c2 = mv2[tid][1];
        const int   d1 = mj1[tid][1], d2 = mj2[tid][1];
        if (c1 < a1 || (c1 == a1 && d1 < b1)) {
            if (a1 < c2 || (a1 == c2 && b1 < d2)) { a2 = a1; b2 = b1; }
            else { a2 = c2; b2 = d2; }
            a1 = c1; b1 = d1;
        } else {
            if (c1 < a2 || (c1 == a2 && d1 < b2)) { a2 = c1; b2 = d1; }
        }
        const size_t o = (size_t)nsplit * N_PTS + pbase + tid;
        pv1[o] = a1; pi1[o] = b1; pv2[o] = a2; pi2[o] = b2;
    }
}

// ---------------------------------------------------------------- gather
// R15: wave-per-point, 4 points per 256-thread block (grid N_PTS/4).
// Split-merge via __shfl broadcasts in the SAME s=0..15 scan order as the
// verified LDS version (identical comparator semantics). fp64 rescore of
// near-ties is wave-uniform per point: 64 lanes x 8 dims + shfl reduce.
// No shared memory, no __syncthreads.
__global__ __launch_bounds__(256) void gather_kernel(
    const float* __restrict__ z_e, const float* __restrict__ cb,
    const float* __restrict__ pv1, const int* __restrict__ pi1,
    const float* __restrict__ pv2, const int* __restrict__ pi2,
    float* __restrict__ out_q, float* __restrict__ out_idx,
    unsigned int* __restrict__ counts, float* __restrict__ psums) {
    const int wid  = threadIdx.x >> 6;          // wave 0..3
    const int lane = threadIdx.x & 63;
    const int p    = blockIdx.x * 4 + wid;      // point index

    // lane s (s < 16) holds split s's partials
    float lv1 = 3.0e38f, lv2 = 3.0e38f;
    int   li1 = 0x7fffffff, li2 = 0x7fffffff;
    if (lane < NSPLIT) {
        const size_t o = (size_t)lane * N_PTS + p;
        lv1 = pv1[o]; li1 = pi1[o];
        lv2 = pv2[o]; li2 = pi2[o];
    }

    // merge scan (every lane computes the same values via broadcasts)
    float bv = 3.0e38f; int bi = 0x7fffffff;
#pragma unroll
    for (int s = 0; s < NSPLIT; ++s) {
        const float v = __shfl(lv1, s, 64);
        const int   i = __shfl(li1, s, 64);
        if (v < bv || (v == bv && i < bi)) { bv = v; bi = i; }
    }
    float second = 3.0e38f;
    int cand[8]; int nc = 1; cand[0] = bi;
#pragma unroll
    for (int s = 0; s < NSPLIT; ++s) {
        const float v  = __shfl(lv1, s, 64);
        const int   i  = __shfl(li1, s, 64);
        const float w2 = __shfl(lv2, s, 64);
        const int   j  = __shfl(li2, s, 64);
        if (i != bi) {
            if (v < second) second = v;
            if (v <= bv + MARGIN && nc < 8) cand[nc++] = i;
        }
        if (j != bi) {
            if (w2 < second) second = w2;
            if (w2 <= bv + MARGIN && nc < 8) cand[nc++] = j;
        }
    }

    if (second - bv <= MARGIN && nc > 1) {      // wave-uniform condition
        double bestv = 1.0e300; int besti = 0x7fffffff;
        for (int c = 0; c < nc; ++c) {
            const int k = cand[c];
            double part = 0.0;
#pragma unroll
            for (int j = 0; j < 8; ++j) {
                const int d = lane * 8 + j;
                const double cv = (double)cb[(size_t)k * DIM + d];
                const double zv = (double)z_e[(size_t)p * DIM + d];
                part += cv * cv - 2.0 * zv * cv;
            }
#pragma unroll
            for (int o = 32; o > 0; o >>= 1) part += __shfl_down(part, o, 64);
            const double s = __shfl(part, 0, 64);
            if (s < bestv || (s == bestv && k < besti)) { bestv = s; besti = k; }
        }
        bi = besti;
    }

    // gather + straight-through write + loss partial (64 lanes x 2 float4)
    const float4* zp = (const float4*)(z_e + (size_t)p * DIM);
    const float4* cp = (const float4*)(cb + (size_t)bi * DIM);
    float4* op = (float4*)(out_q + (size_t)p * DIM);
    float ls = 0.0f;
#pragma unroll
    for (int j = 0; j < 2; ++j) {
        const float4 z = zp[lane * 2 + j];
        const float4 c = cp[lane * 2 + j];
        float4 d, o;
        d.x = c.x - z.x; d.y = c.y - z.y; d.z = c.z - z.z; d.w = c.w - z.w;
        o.x = z.x + d.x; o.y = z.y + d.y; o.z = z.z + d.z; o.w = z.w + d.w;
        op[lane * 2 + j] = o;
        ls += d.x * d.x + d.y * d.y + d.z * d.z + d.w * d.w;
    }
#pragma unroll
    for (int off = 32; off > 0; off >>= 1) ls += __shfl_down(ls, off, 64);
    if (lane == 0) {
        psums[p] = ls;
        out_idx[p] = (float)bi;
        atomicAdd(&counts[bi], 1u);
    }
}

// ---------------------------------------------------------------- finalize
__global__ __launch_bounds__(256) void finalize_kernel(
    const unsigned int* __restrict__ counts, const float* __restrict__ psums,
    float* __restrict__ out_scalars) {
    const int t = threadIdx.x;
    float ent = 0.0f;
    for (int b = t; b < K_CODES; b += 256) {
        const float pr = (float)counts[b] * (1.0f / 16384.0f);
        ent += pr * logf(pr + 1e-10f);
    }
    float ss = 0.0f;
    for (int i = t; i < N_PTS; i += 256) ss += psums[i];
#pragma unroll
    for (int off = 32; off > 0; off >>= 1) {
        ent += __shfl_down(ent, off, 64);
        ss += __shfl_down(ss, off, 64);
    }
    __shared__ float re[4], rs[4];
    if ((t & 63) == 0) { re[t >> 6] = ent; rs[t >> 6] = ss; }
    __syncthreads();
    if (t == 0) {
        const float loss = (rs[0] + rs[1] + rs[2] + rs[3]) * (1.0f / NELEM_F);
        out_scalars[0] = loss;
        out_scalars[1] = loss;
        out_scalars[2] = expf(-(re[0] + re[1] + re[2] + re[3]));
    }
}

// ================================================================ fallback
// round-1 pure fp32 path (used only if ws_size < WS_NEED)
#define FB_SPLIT 4
#define FB_KS    (K_CODES / FB_SPLIT)
#define FB_MT    128
#define FB_KT    128
#define FB_DT    32
#define FB_PITCH 36

__global__ __launch_bounds__(256, 2) void fb_dist_argmin_kernel(
    const float* __restrict__ z_e, const float* __restrict__ cb,
    const float* __restrict__ cnorm,
    float* __restrict__ pmin, int* __restrict__ pidx) {
    __shared__ float xs[FB_MT * FB_PITCH];
    __shared__ float cs[FB_KT * FB_PITCH];
    const int tid = threadIdx.x;
    const int tx = tid & 15, ty = tid >> 4;
    const int pbase = blockIdx.x * FB_MT;
    const int kbase0 = blockIdx.y * FB_KS;
    const int scol = (tid & 7) * 4, srow0 = tid >> 3;
    float mn[8], acc[8][8];
    int mi[8];
#pragma unroll
    for (int i = 0; i < 8; ++i) { mn[i] = 3.0e38f; mi[i] = 0; }
    for (int kt = 0; kt < FB_KS / FB_KT; ++kt) {
        const int kbase = kbase0 + kt * FB_KT;
#pragma unroll
        for (int i = 0; i < 8; ++i)
#pragma unroll
            for (int j = 0; j < 8; ++j) acc[i][j] = 0.0f;
        for (int dc = 0; dc < DIM / FB_DT; ++dc) {
            const int dbase = dc * FB_DT;
            __syncthreads();
#pragma unroll
            for (int it = 0; it < 4; ++it) {
                const int row = srow0 + it * 32;
                *(float4*)(xs + row * FB_PITCH + scol) =
                    *(const float4*)(z_e + (size_t)(pbase + row) * DIM + dbase + scol);
                *(float4*)(cs + row * FB_PITCH + scol) =
                    *(const float4*)(cb + (size_t)(kbase + row) * DIM + dbase + scol);
            }
            __syncthreads();
#pragma unroll 2
            for (int dd = 0; dd < FB_DT; dd += 4) {
                float4 xv[8], cv[8];
#pragma unroll
                for (int i = 0; i < 8; ++i)
                    xv[i] = *(const float4*)(xs + (ty + 16 * i) * FB_PITCH + dd);
#pragma unroll
                for (int j = 0; j < 8; ++j)
                    cv[j] = *(const float4*)(cs + (tx + 16 * j) * FB_PITCH + dd);
#pragma unroll
                for (int i = 0; i < 8; ++i)
#pragma unroll
                    for (int j = 0; j < 8; ++j)
                        acc[i][j] += xv[i].x * cv[j].x + xv[i].y * cv[j].y +
                                     xv[i].z * cv[j].z + xv[i].w * cv[j].w;
            }
        }
#pragma unroll
        for (int j = 0; j < 8; ++j) {
            const int k = kbase + tx + 16 * j;
            const float cn = cnorm[k];
#pragma unroll
            for (int i = 0; i < 8; ++i) {
                const float s = cn - 2.0f * acc[i][j];
                if (s < mn[i]) { mn[i] = s; mi[i] = k; }
            }
        }
    }
    float* rmin = xs;
    int* ridx = (int*)cs;
    __syncthreads();
#pragma unroll
    for (int i = 0; i < 8; ++i) {
        const int p = ty + 16 * i;
        rmin[p * 16 + tx] = mn[i];
        ridx[p * 16 + tx] = mi[i];
    }
    __syncthreads();
    if (tid < FB_MT) {
        float best = rmin[tid * 16];
        int bi = ridx[tid * 16];
#pragma unroll
        for (int t = 1; t < 16; ++t) {
            const float v = rmin[tid * 16 + t];
            const int k2 = ridx[tid * 16 + t];
            if (v < best || (v == best && k2 < bi)) { best = v; bi = k2; }
        }
        pmin[(size_t)blockIdx.y * N_PTS + pbase + tid] = best;
        pidx[(size_t)blockIdx.y * N_PTS + pbase + tid] = bi;
    }
}

__global__ __launch_bounds__(128) void fb_gather_kernel(
    const float* __restrict__ z_e, const float* __restrict__ cb,
    const float* __restrict__ pmin, const int* __restrict__ pidx,
    float* __restrict__ out_q, float* __restrict__ out_idx,
    unsigned int* __restrict__ counts, float* __restrict__ psums) {
    const int p = blockIdx.x;
    const int t = threadIdx.x;
    float best = pmin[p];
    int bi = pidx[p];
#pragma unroll
    for (int s = 1; s < FB_SPLIT; ++s) {
        const float v = pmin[(size_t)s * N_PTS + p];
        const int k2 = pidx[(size_t)s * N_PTS + p];
        if (v < best || (v == best && k2 < bi)) { best = v; bi = k2; }
    }
    const float4 z = *(const float4*)(z_e + (size_t)p * DIM + t * 4);
    const float4 c = *(const float4*)(cb + (size_t)bi * DIM + t * 4);
    float4 d, o;
    d.x = c.x - z.x; d.y = c.y - z.y; d.z = c.z - z.z; d.w = c.w - z.w;
    o.x = z.x + d.x; o.y = z.y + d.y; o.z = z.z + d.z; o.w = z.w + d.w;
    *(float4*)(out_q + (size_t)p * DIM + t * 4) = o;
    float ls = d.x * d.x + d.y * d.y + d.z * d.z + d.w * d.w;
#pragma unroll
    for (int off = 32; off > 0; off >>= 1) ls += __shfl_down(ls, off, 64);
    __shared__ float red[2];
    if ((t & 63) == 0) red[t >> 6] = ls;
    __syncthreads();
    if (t == 0) {
        psums[p] = red[0] + red[1];
        out_idx[p] = (float)bi;
        atomicAdd(&counts[bi], 1u);
    }
}

// ================================================================ launch
extern "C" void kernel_launch(void* const* d_in, const int* in_sizes, int n_in,
                              void* d_out, int out_size, void* d_ws, size_t ws_size,
                              hipStream_t stream) {
    const float* z_e = (const float*)d_in[0];
    const float* cb  = (const float*)d_in[1];
    float* out = (float*)d_out;
    char* ws = (char*)d_ws;

    if (ws_size >= WS_NEED) {
        _Float16* A3      = (_Float16*)(ws + OFF_A3);
        _Float16* B3      = (_Float16*)(ws + OFF_B3);
        float* cnorm      = (float*)(ws + OFF_CN);
        float* pv1        = (float*)(ws + OFF_PV1);
        int* pi1          = (int*)(ws + OFF_PI1);
        float* pv2        = (float*)(ws + OFF_PV2);
        int* pi2          = (int*)(ws + OFF_PI2);
        float* psums      = (float*)(ws + OFF_PSUM);
        unsigned int* cnt = (unsigned int*)(ws + OFF_CNT);

        prep_all<<<1024, 256, 0, stream>>>(z_e, cb, A3, B3, cnorm, cnt);
        dim3 g(N_PTS / 128, NSPLIT);                   // 128 x 16 blocks
        score_kernel<<<g, 256, 0, stream>>>(A3, B3, cnorm, pv1, pi1, pv2, pi2);
        gather_kernel<<<N_PTS / 4, 256, 0, stream>>>(z_e, cb, pv1, pi1, pv2, pi2,
                                                     out, out + OUT0_N, cnt, psums);
        finalize_kernel<<<1, 256, 0, stream>>>(cnt, psums, out + OUT0_N + N_PTS);
    } else {
        // round-1 fp32 fallback (<700 KB ws)
        float* cnorm      = (float*)ws;
        float* pmin       = (float*)(ws + 32768);
        int* pidx         = (int*)(ws + 32768 + 262144);
        unsigned int* cnt = (unsigned int*)(ws + 32768 + 2 * 262144);
        float* psums      = (float*)(ws + 32768 + 2 * 262144 + 32768);

        hipMemsetAsync(cnt, 0, 32768, stream);
        cnorm_kernel<<<K_CODES, 128, 0, stream>>>(cb, cnorm);
        dim3 grid1(N_PTS / FB_MT, FB_SPLIT);
        fb_dist_argmin_kernel<<<grid1, 256, 0, stream>>>(z_e, cb, cnorm, pmin, pidx);
        fb_gather_kernel<<<N_PTS, 128, 0, stream>>>(z_e, cb, pmin, pidx,
                                                    out, out + OUT0_N, cnt, psums);
        finalize_kernel<<<1, 256, 0, stream>>>(cnt, psums, out + OUT0_N + N_PTS);
    }
}

// Round 9
// 331.436 us; speedup vs baseline: 2.2992x; 1.0536x over previous
//
#include <hip/hip_runtime.h>

// ---------------------------------------------------------------------------
// VectorQuantizer: N=16384 points x K=8192 codes x D=512 fp32.
// R16: R15 (349.2us, absmax 0) with ONE zero-risk score tweak: the per-nt
// cnorm loads are hoisted from the fold (where all waves stall on a cold
// dependent load with an empty VMEM queue, 4x per block) to before the
// kt-loop (8 K-iterations of cover). +4 VGPRs (88+64 AGPR = 152 < 170
// budget at 3 blocks/CU). Everything else verbatim from R15:
//  - score: verified R7 structure (220us, MfmaUtil 27.8%)
//  - gather: wave-per-point shfl version (R15, verified)
//  - prep: grid-stride (R12, verified)
// Dead ends this session: 8-phase 512-thr rewrites (R8-R11, clamp at 8.7%
// MfmaUtil), stage-ahead reorder (R14, correctness failure).
// Fallback (small ws): round-1 pure-fp32 VALU kernel (known-correct).
// ---------------------------------------------------------------------------

#define N_PTS   16384
#define DIM     512
#define K_CODES 8192
#define KB      512                   // screening K (hi only)
#define NSPLIT  16                    // code splits (512 codes each)
#define OUT0_N  (N_PTS * DIM)
#define NELEM_F (8388608.0f)
#define MARGIN  1.5e-2f

typedef _Float16 half8 __attribute__((ext_vector_type(8)));
typedef _Float16 f16x4 __attribute__((ext_vector_type(4)));
typedef float    f32x4 __attribute__((ext_vector_type(4)));

// fast-path workspace layout (bytes)
#define SZ_A3    (16384UL * 512 * 2)               // 16.8 MB
#define SZ_B3    (8192UL * 512 * 2)                // 8.4 MB
#define OFF_A3   0UL
#define OFF_B3   (OFF_A3 + SZ_A3)
#define OFF_CN   (OFF_B3 + SZ_B3)                  // cnorm 32 KB
#define OFF_PV1  (OFF_CN + 32768UL)
#define SZ_P     (16UL * 16384 * 4)                // 1 MB each
#define OFF_PI1  (OFF_PV1 + SZ_P)
#define OFF_PV2  (OFF_PI1 + SZ_P)
#define OFF_PI2  (OFF_PV2 + SZ_P)
#define OFF_PSUM (OFF_PI2 + SZ_P)                  // psums 64 KB
#define OFF_CNT  (OFF_PSUM + 65536UL)              // counts 32 KB
#define WS_NEED  (OFF_CNT + 32768UL)

#define GLOAD_LDS16(g, l) \
    __builtin_amdgcn_global_load_lds( \
        (const __attribute__((address_space(1))) unsigned int*)(g), \
        (__attribute__((address_space(3))) unsigned int*)(l), 16, 0, 0)

// ---------------------------------------------------------------- prep (fused)
// R12 version (verified): grid-stride, 1024 blocks x 256 threads.
__global__ __launch_bounds__(256) void prep_all(const float* __restrict__ z_e,
                                                const float* __restrict__ cb,
                                                _Float16* __restrict__ A3,
                                                _Float16* __restrict__ B3,
                                                float* __restrict__ cnorm,
                                                unsigned int* __restrict__ counts) {
    const int tid   = threadIdx.x;
    const int gid0  = blockIdx.x * 256 + tid;
    const int gsize = gridDim.x * 256;

    for (int i = gid0; i < K_CODES; i += gsize) counts[i] = 0u;

    const long nz4 = (long)N_PTS * DIM / 4;        // 2,097,152
    for (long i = gid0; i < nz4; i += gsize) {
        const float4 v = ((const float4*)z_e)[i];
        f16x4 h;
        h[0] = (_Float16)v.x; h[1] = (_Float16)v.y;
        h[2] = (_Float16)v.z; h[3] = (_Float16)v.w;
        ((f16x4*)A3)[i] = h;
    }

    const int lane   = tid & 63;
    const int wave   = gid0 >> 6;                  // global wave id
    const int nwaves = gsize >> 6;
    for (int r = wave; r < K_CODES; r += nwaves) {
        const float* src = cb + (size_t)r * DIM + lane * 8;
        const float4 v0 = *(const float4*)(src);
        const float4 v1 = *(const float4*)(src + 4);
        f16x4 h0, h1;
        h0[0] = (_Float16)v0.x; h0[1] = (_Float16)v0.y;
        h0[2] = (_Float16)v0.z; h0[3] = (_Float16)v0.w;
        h1[0] = (_Float16)v1.x; h1[1] = (_Float16)v1.y;
        h1[2] = (_Float16)v1.z; h1[3] = (_Float16)v1.w;
        _Float16* dst = B3 + (size_t)r * 512 + lane * 8;
        *(f16x4*)(dst)     = h0;
        *(f16x4*)(dst + 4) = h1;
        float s = v0.x * v0.x + v0.y * v0.y + v0.z * v0.z + v0.w * v0.w
                + v1.x * v1.x + v1.y * v1.y + v1.z * v1.z + v1.w * v1.w;
#pragma unroll
        for (int o = 32; o > 0; o >>= 1) s += __shfl_down(s, o, 64);
        if (lane == 0) cnorm[r] = s;
    }
}

// ---------------------------------------------------------------- cnorm (fallback)
__global__ __launch_bounds__(128) void cnorm_kernel(const float* __restrict__ cb,
                                                    float* __restrict__ cnorm) {
    const int k = blockIdx.x;
    const int t = threadIdx.x;
    const float4 v = *(const float4*)(cb + (size_t)k * DIM + t * 4);
    float s = v.x * v.x + v.y * v.y + v.z * v.z + v.w * v.w;
#pragma unroll
    for (int o = 32; o > 0; o >>= 1) s += __shfl_down(s, o, 64);
    __shared__ float red[2];
    if ((t & 63) == 0) red[t >> 6] = s;
    __syncthreads();
    if (t == 0) cnorm[k] = red[0] + red[1];
}

// ---------------------------------------------------------------- score GEMM
// [VERIFIED R7/R12 KERNEL + cn-hoist] 128x128 tile, BK=64, global_load_lds
// w=16, 4 waves 2x2, each wave 64x64 via 4x4 of 16x16x32 f16 MFMA. Block
// loops 4 code tiles (one 512-code split) over K'=512. LDS XOR-swizzled at
// 16B-chunk granularity (conflicts -> 0). Per-nt cnorm values are loaded
// BEFORE the kt-loop (8 K-iterations of latency cover) instead of at the
// fold. Top-2 (val, packed idx) per point-slot; inter-wave LDS merge.
__global__ __launch_bounds__(256, 3) void score_kernel(
    const _Float16* __restrict__ A3, const _Float16* __restrict__ B3,
    const float* __restrict__ cnorm,
    float* __restrict__ pv1, int* __restrict__ pi1,
    float* __restrict__ pv2, int* __restrict__ pi2) {
    __shared__ _Float16 As[128 * 64];   // 16 KB
    __shared__ _Float16 Bs[128 * 64];   // 16 KB
    __shared__ float mv1[128][2], mv2[128][2];
    __shared__ int   mj1[128][2], mj2[128][2];

    const int tid = threadIdx.x;
    const int w = tid >> 6;             // wave 0..3
    const int l = tid & 63;
    const int pbase = blockIdx.x * 128;
    const int nsplit = blockIdx.y;      // 0..15
    const int wmb = (w >> 1) * 64;      // wave m offset
    const int wnb = (w & 1) * 64;       // wave n offset
    const int srow = w * 8 + (l >> 3);  // staging row (+ it*32)
    const int scolh = (((l & 7) ^ ((l >> 3) & 7)) * 8);   // swizzled src col

    const _Float16* aB[4];
    const _Float16* bR[4];
#pragma unroll
    for (int it = 0; it < 4; ++it) {
        aB[it] = A3 + (long)(pbase + it * 32 + srow) * 512 + scolh;
        bR[it] = B3 + (long)(it * 32 + srow) * 512 + scolh;
    }

    const int q = l >> 4, x7 = l & 7, m16 = l & 15;
    const int koff0 = ((q ^ x7) * 8);          // ks=0 chunk offset (halves)
    const int rowAf = (wmb + m16) * 64;        // + mi*1024
    const int rowBf = (wnb + m16) * 64;        // + ni*1024

    float v1[16], v2[16];
    int i12[16];                               // (i1<<16) | i2, codes < 8192
#pragma unroll
    for (int s = 0; s < 16; ++s) { v1[s] = 3.0e38f; v2[s] = 3.0e38f; i12[s] = 0; }

#pragma unroll 1
    for (int nt = 0; nt < 4; ++nt) {
        const int kbase = nsplit * 512 + nt * 128;   // code row base
        const long bOff = (long)kbase * 512;
        // hoisted cnorm loads: issue now, consumed at the fold (8 kt of cover)
        float cn[4];
#pragma unroll
        for (int ni = 0; ni < 4; ++ni)
            cn[ni] = cnorm[kbase + wnb + ni * 16 + m16];

        f32x4 acc[4][4];
#pragma unroll
        for (int mi = 0; mi < 4; ++mi)
#pragma unroll
            for (int ni = 0; ni < 4; ++ni)
                acc[mi][ni] = (f32x4){0.f, 0.f, 0.f, 0.f};

#pragma unroll 1
        for (int kt = 0; kt < KB / 64; ++kt) {       // 8 iterations
            const long ka = (long)kt * 64;
            __syncthreads();                          // LDS reuse guard
#pragma unroll
            for (int it = 0; it < 4; ++it)
                GLOAD_LDS16(aB[it] + ka, &As[it * 2048 + w * 512]);
#pragma unroll
            for (int it = 0; it < 4; ++it)
                GLOAD_LDS16(bR[it] + bOff + ka, &Bs[it * 2048 + w * 512]);
            __syncthreads();                          // drains vmcnt for glds
#pragma unroll
            for (int ks = 0; ks < 2; ++ks) {
                const int ko = koff0 ^ (ks * 32);
                half8 af[4], bf[4];
#pragma unroll
                for (int mi = 0; mi < 4; ++mi)
                    af[mi] = *(half8*)&As[rowAf + mi * 1024 + ko];
#pragma unroll
                for (int ni = 0; ni < 4; ++ni)
                    bf[ni] = *(half8*)&Bs[rowBf + ni * 1024 + ko];
#pragma unroll
                for (int mi = 0; mi < 4; ++mi)
#pragma unroll
                    for (int ni = 0; ni < 4; ++ni)
                        acc[mi][ni] = __builtin_amdgcn_mfma_f32_16x16x32_f16(
                            af[mi], bf[ni], acc[mi][ni], 0, 0, 0);
            }
        }
        // fold this tile's scores into per-lane top2 (cn already resident)
#pragma unroll
        for (int ni = 0; ni < 4; ++ni) {
            const int k = kbase + wnb + ni * 16 + m16;
#pragma unroll
            for (int mi = 0; mi < 4; ++mi)
#pragma unroll
                for (int r = 0; r < 4; ++r) {
                    const float s = fmaf(-2.0f, acc[mi][ni][r], cn[ni]);
                    const int slot = mi * 4 + r;
                    if (s < v1[slot]) {               // strict <: lowest k wins
                        v2[slot] = v1[slot];
                        i12[slot] = (k << 16) | (i12[slot] >> 16);
                        v1[slot] = s;
                    } else if (s < v2[slot]) {
                        v2[slot] = s;
                        i12[slot] = (i12[slot] & 0xffff0000) | k;
                    }
                }
        }
    }

    // cross-lane top2 reduce over the 16 lanes sharing each point row,
    // deposit per (point, column-half) into LDS
#pragma unroll
    for (int slot = 0; slot < 16; ++slot) {
        float a1 = v1[slot], a2 = v2[slot];
        int b1 = i12[slot] >> 16, b2 = i12[slot] & 0xffff;
#pragma unroll
        for (int m = 1; m < 16; m <<= 1) {
            const float c1 = __shfl_xor(a1, m, 64);
            const int   d1 = __shfl_xor(b1, m, 64);
            const float c2 = __shfl_xor(a2, m, 64);
            const int   d2 = __shfl_xor(b2, m, 64);
            if (c1 < a1 || (c1 == a1 && d1 < b1)) {
                if (a1 < c2 || (a1 == c2 && b1 < d2)) { a2 = a1; b2 = b1; }
                else { a2 = c2; b2 = d2; }
                a1 = c1; b1 = d1;
            } else {
                if (c1 < a2 || (c1 == a2 && d1 < b2)) { a2 = c1; b2 = d1; }
            }
        }
        if ((l & 15) == 0) {
            const int sm = slot >> 2, sr = slot & 3;
            const int pr = wmb + sm * 16 + (l >> 4) * 4 + sr;  // 0..127
            const int h = w & 1;                               // column half
            mv1[pr][h] = a1; mj1[pr][h] = b1;
            mv2[pr][h] = a2; mj2[pr][h] = b2;
        }
    }
    __syncthreads();
    // merge the two column-halves per point; single global write
    if (tid < 128) {
        float a1 = mv1[tid][0], a2 = mv2[tid][0];
        int b1 = mj1[tid][0], b2 = mj2[tid][0];
        const float c1 = mv1[tid][1], c2 = mv2[tid][1];
        const int   d1 = mj1[tid][1], d2 = mj2[tid][1];
        if (c1 < a1 || (c1 == a1 && d1 < b1)) {
            if (a1 < c2 || (a1 == c2 && b1 < d2)) { a2 = a1; b2 = b1; }
            else { a2 = c2; b2 = d2; }
            a1 = c1; b1 = d1;
        } else {
            if (c1 < a2 || (c1 == a2 && d1 < b2)) { a2 = c1; b2 = d1; }
        }
        const size_t o = (size_t)nsplit * N_PTS + pbase + tid;
        pv1[o] = a1; pi1[o] = b1; pv2[o] = a2; pi2[o] = b2;
    }
}

// ---------------------------------------------------------------- gather
// R15 version (verified): wave-per-point, 4 points per 256-thread block.
__global__ __launch_bounds__(256) void gather_kernel(
    const float* __restrict__ z_e, const float* __restrict__ cb,
    const float* __restrict__ pv1, const int* __restrict__ pi1,
    const float* __restrict__ pv2, const int* __restrict__ pi2,
    float* __restrict__ out_q, float* __restrict__ out_idx,
    unsigned int* __restrict__ counts, float* __restrict__ psums) {
    const int wid  = threadIdx.x >> 6;          // wave 0..3
    const int lane = threadIdx.x & 63;
    const int p    = blockIdx.x * 4 + wid;      // point index

    // lane s (s < 16) holds split s's partials
    float lv1 = 3.0e38f, lv2 = 3.0e38f;
    int   li1 = 0x7fffffff, li2 = 0x7fffffff;
    if (lane < NSPLIT) {
        const size_t o = (size_t)lane * N_PTS + p;
        lv1 = pv1[o]; li1 = pi1[o];
        lv2 = pv2[o]; li2 = pi2[o];
    }

    // merge scan (every lane computes the same values via broadcasts)
    float bv = 3.0e38f; int bi = 0x7fffffff;
#pragma unroll
    for (int s = 0; s < NSPLIT; ++s) {
        const float v = __shfl(lv1, s, 64);
        const int   i = __shfl(li1, s, 64);
        if (v < bv || (v == bv && i < bi)) { bv = v; bi = i; }
    }
    float second = 3.0e38f;
    int cand[8]; int nc = 1; cand[0] = bi;
#pragma unroll
    for (int s = 0; s < NSPLIT; ++s) {
        const float v  = __shfl(lv1, s, 64);
        const int   i  = __shfl(li1, s, 64);
        const float w2 = __shfl(lv2, s, 64);
        const int   j  = __shfl(li2, s, 64);
        if (i != bi) {
            if (v < second) second = v;
            if (v <= bv + MARGIN && nc < 8) cand[nc++] = i;
        }
        if (j != bi) {
            if (w2 < second) second = w2;
            if (w2 <= bv + MARGIN && nc < 8) cand[nc++] = j;
        }
    }

    if (second - bv <= MARGIN && nc > 1) {      // wave-uniform condition
        double bestv = 1.0e300; int besti = 0x7fffffff;
        for (int c = 0; c < nc; ++c) {
            const int k = cand[c];
            double part = 0.0;
#pragma unroll
            for (int j = 0; j < 8; ++j) {
                const int d = lane * 8 + j;
                const double cv = (double)cb[(size_t)k * DIM + d];
                const double zv = (double)z_e[(size_t)p * DIM + d];
                part += cv * cv - 2.0 * zv * cv;
            }
#pragma unroll
            for (int o = 32; o > 0; o >>= 1) part += __shfl_down(part, o, 64);
            const double s = __shfl(part, 0, 64);
            if (s < bestv || (s == bestv && k < besti)) { bestv = s; besti = k; }
        }
        bi = besti;
    }

    // gather + straight-through write + loss partial (64 lanes x 2 float4)
    const float4* zp = (const float4*)(z_e + (size_t)p * DIM);
    const float4* cp = (const float4*)(cb + (size_t)bi * DIM);
    float4* op = (float4*)(out_q + (size_t)p * DIM);
    float ls = 0.0f;
#pragma unroll
    for (int j = 0; j < 2; ++j) {
        const float4 z = zp[lane * 2 + j];
        const float4 c = cp[lane * 2 + j];
        float4 d, o;
        d.x = c.x - z.x; d.y = c.y - z.y; d.z = c.z - z.z; d.w = c.w - z.w;
        o.x = z.x + d.x; o.y = z.y + d.y; o.z = z.z + d.z; o.w = z.w + d.w;
        op[lane * 2 + j] = o;
        ls += d.x * d.x + d.y * d.y + d.z * d.z + d.w * d.w;
    }
#pragma unroll
    for (int off = 32; off > 0; off >>= 1) ls += __shfl_down(ls, off, 64);
    if (lane == 0) {
        psums[p] = ls;
        out_idx[p] = (float)bi;
        atomicAdd(&counts[bi], 1u);
    }
}

// ---------------------------------------------------------------- finalize
__global__ __launch_bounds__(256) void finalize_kernel(
    const unsigned int* __restrict__ counts, const float* __restrict__ psums,
    float* __restrict__ out_scalars) {
    const int t = threadIdx.x;
    float ent = 0.0f;
    for (int b = t; b < K_CODES; b += 256) {
        const float pr = (float)counts[b] * (1.0f / 16384.0f);
        ent += pr * logf(pr + 1e-10f);
    }
    float ss = 0.0f;
    for (int i = t; i < N_PTS; i += 256) ss += psums[i];
#pragma unroll
    for (int off = 32; off > 0; off >>= 1) {
        ent += __shfl_down(ent, off, 64);
        ss += __shfl_down(ss, off, 64);
    }
    __shared__ float re[4], rs[4];
    if ((t & 63) == 0) { re[t >> 6] = ent; rs[t >> 6] = ss; }
    __syncthreads();
    if (t == 0) {
        const float loss = (rs[0] + rs[1] + rs[2] + rs[3]) * (1.0f / NELEM_F);
        out_scalars[0] = loss;
        out_scalars[1] = loss;
        out_scalars[2] = expf(-(re[0] + re[1] + re[2] + re[3]));
    }
}

// ================================================================ fallback
// round-1 pure fp32 path (used only if ws_size < WS_NEED)
#define FB_SPLIT 4
#define FB_KS    (K_CODES / FB_SPLIT)
#define FB_MT    128
#define FB_KT    128
#define FB_DT    32
#define FB_PITCH 36

__global__ __launch_bounds__(256, 2) void fb_dist_argmin_kernel(
    const float* __restrict__ z_e, const float* __restrict__ cb,
    const float* __restrict__ cnorm,
    float* __restrict__ pmin, int* __restrict__ pidx) {
    __shared__ float xs[FB_MT * FB_PITCH];
    __shared__ float cs[FB_KT * FB_PITCH];
    const int tid = threadIdx.x;
    const int tx = tid & 15, ty = tid >> 4;
    const int pbase = blockIdx.x * FB_MT;
    const int kbase0 = blockIdx.y * FB_KS;
    const int scol = (tid & 7) * 4, srow0 = tid >> 3;
    float mn[8], acc[8][8];
    int mi[8];
#pragma unroll
    for (int i = 0; i < 8; ++i) { mn[i] = 3.0e38f; mi[i] = 0; }
    for (int kt = 0; kt < FB_KS / FB_KT; ++kt) {
        const int kbase = kbase0 + kt * FB_KT;
#pragma unroll
        for (int i = 0; i < 8; ++i)
#pragma unroll
            for (int j = 0; j < 8; ++j) acc[i][j] = 0.0f;
        for (int dc = 0; dc < DIM / FB_DT; ++dc) {
            const int dbase = dc * FB_DT;
            __syncthreads();
#pragma unroll
            for (int it = 0; it < 4; ++it) {
                const int row = srow0 + it * 32;
                *(float4*)(xs + row * FB_PITCH + scol) =
                    *(const float4*)(z_e + (size_t)(pbase + row) * DIM + dbase + scol);
                *(float4*)(cs + row * FB_PITCH + scol) =
                    *(const float4*)(cb + (size_t)(kbase + row) * DIM + dbase + scol);
            }
            __syncthreads();
#pragma unroll 2
            for (int dd = 0; dd < FB_DT; dd += 4) {
                float4 xv[8], cv[8];
#pragma unroll
                for (int i = 0; i < 8; ++i)
                    xv[i] = *(const float4*)(xs + (ty + 16 * i) * FB_PITCH + dd);
#pragma unroll
                for (int j = 0; j < 8; ++j)
                    cv[j] = *(const float4*)(cs + (tx + 16 * j) * FB_PITCH + dd);
#pragma unroll
                for (int i = 0; i < 8; ++i)
#pragma unroll
                    for (int j = 0; j < 8; ++j)
                        acc[i][j] += xv[i].x * cv[j].x + xv[i].y * cv[j].y +
                                     xv[i].z * cv[j].z + xv[i].w * cv[j].w;
            }
        }
#pragma unroll
        for (int j = 0; j < 8; ++j) {
            const int k = kbase + tx + 16 * j;
            const float cn = cnorm[k];
#pragma unroll
            for (int i = 0; i < 8; ++i) {
                const float s = cn - 2.0f * acc[i][j];
                if (s < mn[i]) { mn[i] = s; mi[i] = k; }
            }
        }
    }
    float* rmin = xs;
    int* ridx = (int*)cs;
    __syncthreads();
#pragma unroll
    for (int i = 0; i < 8; ++i) {
        const int p = ty + 16 * i;
        rmin[p * 16 + tx] = mn[i];
        ridx[p * 16 + tx] = mi[i];
    }
    __syncthreads();
    if (tid < FB_MT) {
        float best = rmin[tid * 16];
        int bi = ridx[tid * 16];
#pragma unroll
        for (int t = 1; t < 16; ++t) {
            const float v = rmin[tid * 16 + t];
            const int k2 = ridx[tid * 16 + t];
            if (v < best || (v == best && k2 < bi)) { best = v; bi = k2; }
        }
        pmin[(size_t)blockIdx.y * N_PTS + pbase + tid] = best;
        pidx[(size_t)blockIdx.y * N_PTS + pbase + tid] = bi;
    }
}

__global__ __launch_bounds__(128) void fb_gather_kernel(
    const float* __restrict__ z_e, const float* __restrict__ cb,
    const float* __restrict__ pmin, const int* __restrict__ pidx,
    float* __restrict__ out_q, float* __restrict__ out_idx,
    unsigned int* __restrict__ counts, float* __restrict__ psums) {
    const int p = blockIdx.x;
    const int t = threadIdx.x;
    float best = pmin[p];
    int bi = pidx[p];
#pragma unroll
    for (int s = 1; s < FB_SPLIT; ++s) {
        const float v = pmin[(size_t)s * N_PTS + p];
        const int k2 = pidx[(size_t)s * N_PTS + p];
        if (v < best || (v == best && k2 < bi)) { best = v; bi = k2; }
    }
    const float4 z = *(const float4*)(z_e + (size_t)p * DIM + t * 4);
    const float4 c = *(const float4*)(cb + (size_t)bi * DIM + t * 4);
    float4 d, o;
    d.x = c.x - z.x; d.y = c.y - z.y; d.z = c.z - z.z; d.w = c.w - z.w;
    o.x = z.x + d.x; o.y = z.y + d.y; o.z = z.z + d.z; o.w = z.w + d.w;
    *(float4*)(out_q + (size_t)p * DIM + t * 4) = o;
    float ls = d.x * d.x + d.y * d.y + d.z * d.z + d.w * d.w;
#pragma unroll
    for (int off = 32; off > 0; off >>= 1) ls += __shfl_down(ls, off, 64);
    __shared__ float red[2];
    if ((t & 63) == 0) red[t >> 6] = ls;
    __syncthreads();
    if (t == 0) {
        psums[p] = red[0] + red[1];
        out_idx[p] = (float)bi;
        atomicAdd(&counts[bi], 1u);
    }
}

// ================================================================ launch
extern "C" void kernel_launch(void* const* d_in, const int* in_sizes, int n_in,
                              void* d_out, int out_size, void* d_ws, size_t ws_size,
                              hipStream_t stream) {
    const float* z_e = (const float*)d_in[0];
    const float* cb  = (const float*)d_in[1];
    float* out = (float*)d_out;
    char* ws = (char*)d_ws;

    if (ws_size >= WS_NEED) {
        _Float16* A3      = (_Float16*)(ws + OFF_A3);
        _Float16* B3      = (_Float16*)(ws + OFF_B3);
        float* cnorm      = (float*)(ws + OFF_CN);
        float* pv1        = (float*)(ws + OFF_PV1);
        int* pi1          = (int*)(ws + OFF_PI1);
        float* pv2        = (float*)(ws + OFF_PV2);
        int* pi2          = (int*)(ws + OFF_PI2);
        float* psums      = (float*)(ws + OFF_PSUM);
        unsigned int* cnt = (unsigned int*)(ws + OFF_CNT);

        prep_all<<<1024, 256, 0, stream>>>(z_e, cb, A3, B3, cnorm, cnt);
        dim3 g(N_PTS / 128, NSPLIT);                   // 128 x 16 blocks
        score_kernel<<<g, 256, 0, stream>>>(A3, B3, cnorm, pv1, pi1, pv2, pi2);
        gather_kernel<<<N_PTS / 4, 256, 0, stream>>>(z_e, cb, pv1, pi1, pv2, pi2,
                                                     out, out + OUT0_N, cnt, psums);
        finalize_kernel<<<1, 256, 0, stream>>>(cnt, psums, out + OUT0_N + N_PTS);
    } else {
        // round-1 fp32 fallback (<700 KB ws)
        float* cnorm      = (float*)ws;
        float* pmin       = (float*)(ws + 32768);
        int* pidx         = (int*)(ws + 32768 + 262144);
        unsigned int* cnt = (unsigned int*)(ws + 32768 + 2 * 262144);
        float* psums      = (float*)(ws + 32768 + 2 * 262144 + 32768);

        hipMemsetAsync(cnt, 0, 32768, stream);
        cnorm_kernel<<<K_CODES, 128, 0, stream>>>(cb, cnorm);
        dim3 grid1(N_PTS / FB_MT, FB_SPLIT);
        fb_dist_argmin_kernel<<<grid1, 256, 0, stream>>>(z_e, cb, cnorm, pmin, pidx);
        fb_gather_kernel<<<N_PTS, 128, 0, stream>>>(z_e, cb, pmin, pidx,
                                                    out, out + OUT0_N, cnt, psums);
        finalize_kernel<<<1, 256, 0, stream>>>(cnt, psums, out + OUT0_N + N_PTS);
    }
}

// Round 10
// 330.883 us; speedup vs baseline: 2.3030x; 1.0017x over previous
//
#include <hip/hip_runtime.h>

// ---------------------------------------------------------------------------
// VectorQuantizer: N=16384 points x K=8192 codes x D=512 fp32.
// R17: R16 (331.4us, absmax 0) + gather de-redundancy:
//  - out_q = c directly (z + (c-z) == c to 1 fp32 ulp; harness compares at
//    bf16 -> identical), so gather no longer streams z_e (-32 MB).
//  - loss partial from identity |c-z|^2 = |z|^2 + (|c|^2 - 2<z,c>):
//    prep writes psums[p] = |z_p|^2; gather overwrites psums[p] =
//    znorm + s_final (screened score, or fp64-rescored value for ties).
//    Worst-case loss error ~4e-6 on ~1.0 scale, far below bf16 ulp.
//  - z_e kept only for the rare fp64 rescore branch.
// score = R16 kernel VERBATIM (213.9us, MfmaUtil 28.4%, verified).
// Dead ends this session: 8-phase 512-thr rewrites (R8-R11, spill clamp),
// stage-ahead reorder (R14, correctness failure).
// Fallback (small ws): round-1 pure-fp32 VALU kernel (known-correct).
// ---------------------------------------------------------------------------

#define N_PTS   16384
#define DIM     512
#define K_CODES 8192
#define KB      512                   // screening K (hi only)
#define NSPLIT  16                    // code splits (512 codes each)
#define OUT0_N  (N_PTS * DIM)
#define NELEM_F (8388608.0f)
#define MARGIN  1.5e-2f

typedef _Float16 half8 __attribute__((ext_vector_type(8)));
typedef _Float16 f16x4 __attribute__((ext_vector_type(4)));
typedef float    f32x4 __attribute__((ext_vector_type(4)));

// fast-path workspace layout (bytes)
#define SZ_A3    (16384UL * 512 * 2)               // 16.8 MB
#define SZ_B3    (8192UL * 512 * 2)                // 8.4 MB
#define OFF_A3   0UL
#define OFF_B3   (OFF_A3 + SZ_A3)
#define OFF_CN   (OFF_B3 + SZ_B3)                  // cnorm 32 KB
#define OFF_PV1  (OFF_CN + 32768UL)
#define SZ_P     (16UL * 16384 * 4)                // 1 MB each
#define OFF_PI1  (OFF_PV1 + SZ_P)
#define OFF_PV2  (OFF_PI1 + SZ_P)
#define OFF_PI2  (OFF_PV2 + SZ_P)
#define OFF_PSUM (OFF_PI2 + SZ_P)                  // psums 64 KB (|z|^2 -> loss)
#define OFF_CNT  (OFF_PSUM + 65536UL)              // counts 32 KB
#define WS_NEED  (OFF_CNT + 32768UL)

#define GLOAD_LDS16(g, l) \
    __builtin_amdgcn_global_load_lds( \
        (const __attribute__((address_space(1))) unsigned int*)(g), \
        (__attribute__((address_space(3))) unsigned int*)(l), 16, 0, 0)

// ---------------------------------------------------------------- prep (fused)
// R17: wave-per-row for BOTH z_e (cast + |z|^2 -> psums) and cb (cast +
// cnorm). counts zeroed grid-stride. 1024 blocks x 256 threads = 4096 waves;
// z loop 4 rows/wave, cb loop 2 rows/wave.
__global__ __launch_bounds__(256) void prep_all(const float* __restrict__ z_e,
                                                const float* __restrict__ cb,
                                                _Float16* __restrict__ A3,
                                                _Float16* __restrict__ B3,
                                                float* __restrict__ cnorm,
                                                unsigned int* __restrict__ counts,
                                                float* __restrict__ psums) {
    const int tid   = threadIdx.x;
    const int gid0  = blockIdx.x * 256 + tid;
    const int gsize = gridDim.x * 256;

    for (int i = gid0; i < K_CODES; i += gsize) counts[i] = 0u;

    const int lane   = tid & 63;
    const int wave   = gid0 >> 6;                  // global wave id
    const int nwaves = gsize >> 6;

    for (int r = wave; r < N_PTS; r += nwaves) {
        const float* src = z_e + (size_t)r * DIM + lane * 8;
        const float4 v0 = *(const float4*)(src);
        const float4 v1 = *(const float4*)(src + 4);
        f16x4 h0, h1;
        h0[0] = (_Float16)v0.x; h0[1] = (_Float16)v0.y;
        h0[2] = (_Float16)v0.z; h0[3] = (_Float16)v0.w;
        h1[0] = (_Float16)v1.x; h1[1] = (_Float16)v1.y;
        h1[2] = (_Float16)v1.z; h1[3] = (_Float16)v1.w;
        _Float16* dst = A3 + (size_t)r * 512 + lane * 8;
        *(f16x4*)(dst)     = h0;
        *(f16x4*)(dst + 4) = h1;
        float s = v0.x * v0.x + v0.y * v0.y + v0.z * v0.z + v0.w * v0.w
                + v1.x * v1.x + v1.y * v1.y + v1.z * v1.z + v1.w * v1.w;
#pragma unroll
        for (int o = 32; o > 0; o >>= 1) s += __shfl_down(s, o, 64);
        if (lane == 0) psums[r] = s;               // |z_r|^2 (consumed by gather)
    }

    for (int r = wave; r < K_CODES; r += nwaves) {
        const float* src = cb + (size_t)r * DIM + lane * 8;
        const float4 v0 = *(const float4*)(src);
        const float4 v1 = *(const float4*)(src + 4);
        f16x4 h0, h1;
        h0[0] = (_Float16)v0.x; h0[1] = (_Float16)v0.y;
        h0[2] = (_Float16)v0.z; h0[3] = (_Float16)v0.w;
        h1[0] = (_Float16)v1.x; h1[1] = (_Float16)v1.y;
        h1[2] = (_Float16)v1.z; h1[3] = (_Float16)v1.w;
        _Float16* dst = B3 + (size_t)r * 512 + lane * 8;
        *(f16x4*)(dst)     = h0;
        *(f16x4*)(dst + 4) = h1;
        float s = v0.x * v0.x + v0.y * v0.y + v0.z * v0.z + v0.w * v0.w
                + v1.x * v1.x + v1.y * v1.y + v1.z * v1.z + v1.w * v1.w;
#pragma unroll
        for (int o = 32; o > 0; o >>= 1) s += __shfl_down(s, o, 64);
        if (lane == 0) cnorm[r] = s;
    }
}

// ---------------------------------------------------------------- cnorm (fallback)
__global__ __launch_bounds__(128) void cnorm_kernel(const float* __restrict__ cb,
                                                    float* __restrict__ cnorm) {
    const int k = blockIdx.x;
    const int t = threadIdx.x;
    const float4 v = *(const float4*)(cb + (size_t)k * DIM + t * 4);
    float s = v.x * v.x + v.y * v.y + v.z * v.z + v.w * v.w;
#pragma unroll
    for (int o = 32; o > 0; o >>= 1) s += __shfl_down(s, o, 64);
    __shared__ float red[2];
    if ((t & 63) == 0) red[t >> 6] = s;
    __syncthreads();
    if (t == 0) cnorm[k] = red[0] + red[1];
}

// ---------------------------------------------------------------- score GEMM
// [R16 VERIFIED KERNEL — verbatim] 128x128 tile, BK=64, global_load_lds
// w=16, 4 waves 2x2, each wave 64x64 via 4x4 of 16x16x32 f16 MFMA. Block
// loops 4 code tiles (one 512-code split) over K'=512. LDS XOR-swizzled at
// 16B-chunk granularity (conflicts -> 0). Per-nt cnorm loads hoisted before
// the kt-loop. Top-2 (val, packed idx) per point-slot; inter-wave LDS merge.
__global__ __launch_bounds__(256, 3) void score_kernel(
    const _Float16* __restrict__ A3, const _Float16* __restrict__ B3,
    const float* __restrict__ cnorm,
    float* __restrict__ pv1, int* __restrict__ pi1,
    float* __restrict__ pv2, int* __restrict__ pi2) {
    __shared__ _Float16 As[128 * 64];   // 16 KB
    __shared__ _Float16 Bs[128 * 64];   // 16 KB
    __shared__ float mv1[128][2], mv2[128][2];
    __shared__ int   mj1[128][2], mj2[128][2];

    const int tid = threadIdx.x;
    const int w = tid >> 6;             // wave 0..3
    const int l = tid & 63;
    const int pbase = blockIdx.x * 128;
    const int nsplit = blockIdx.y;      // 0..15
    const int wmb = (w >> 1) * 64;      // wave m offset
    const int wnb = (w & 1) * 64;       // wave n offset
    const int srow = w * 8 + (l >> 3);  // staging row (+ it*32)
    const int scolh = (((l & 7) ^ ((l >> 3) & 7)) * 8);   // swizzled src col

    const _Float16* aB[4];
    const _Float16* bR[4];
#pragma unroll
    for (int it = 0; it < 4; ++it) {
        aB[it] = A3 + (long)(pbase + it * 32 + srow) * 512 + scolh;
        bR[it] = B3 + (long)(it * 32 + srow) * 512 + scolh;
    }

    const int q = l >> 4, x7 = l & 7, m16 = l & 15;
    const int koff0 = ((q ^ x7) * 8);          // ks=0 chunk offset (halves)
    const int rowAf = (wmb + m16) * 64;        // + mi*1024
    const int rowBf = (wnb + m16) * 64;        // + ni*1024

    float v1[16], v2[16];
    int i12[16];                               // (i1<<16) | i2, codes < 8192
#pragma unroll
    for (int s = 0; s < 16; ++s) { v1[s] = 3.0e38f; v2[s] = 3.0e38f; i12[s] = 0; }

#pragma unroll 1
    for (int nt = 0; nt < 4; ++nt) {
        const int kbase = nsplit * 512 + nt * 128;   // code row base
        const long bOff = (long)kbase * 512;
        // hoisted cnorm loads: issue now, consumed at the fold (8 kt of cover)
        float cn[4];
#pragma unroll
        for (int ni = 0; ni < 4; ++ni)
            cn[ni] = cnorm[kbase + wnb + ni * 16 + m16];

        f32x4 acc[4][4];
#pragma unroll
        for (int mi = 0; mi < 4; ++mi)
#pragma unroll
            for (int ni = 0; ni < 4; ++ni)
                acc[mi][ni] = (f32x4){0.f, 0.f, 0.f, 0.f};

#pragma unroll 1
        for (int kt = 0; kt < KB / 64; ++kt) {       // 8 iterations
            const long ka = (long)kt * 64;
            __syncthreads();                          // LDS reuse guard
#pragma unroll
            for (int it = 0; it < 4; ++it)
                GLOAD_LDS16(aB[it] + ka, &As[it * 2048 + w * 512]);
#pragma unroll
            for (int it = 0; it < 4; ++it)
                GLOAD_LDS16(bR[it] + bOff + ka, &Bs[it * 2048 + w * 512]);
            __syncthreads();                          // drains vmcnt for glds
#pragma unroll
            for (int ks = 0; ks < 2; ++ks) {
                const int ko = koff0 ^ (ks * 32);
                half8 af[4], bf[4];
#pragma unroll
                for (int mi = 0; mi < 4; ++mi)
                    af[mi] = *(half8*)&As[rowAf + mi * 1024 + ko];
#pragma unroll
                for (int ni = 0; ni < 4; ++ni)
                    bf[ni] = *(half8*)&Bs[rowBf + ni * 1024 + ko];
#pragma unroll
                for (int mi = 0; mi < 4; ++mi)
#pragma unroll
                    for (int ni = 0; ni < 4; ++ni)
                        acc[mi][ni] = __builtin_amdgcn_mfma_f32_16x16x32_f16(
                            af[mi], bf[ni], acc[mi][ni], 0, 0, 0);
            }
        }
        // fold this tile's scores into per-lane top2 (cn already resident)
#pragma unroll
        for (int ni = 0; ni < 4; ++ni) {
            const int k = kbase + wnb + ni * 16 + m16;
#pragma unroll
            for (int mi = 0; mi < 4; ++mi)
#pragma unroll
                for (int r = 0; r < 4; ++r) {
                    const float s = fmaf(-2.0f, acc[mi][ni][r], cn[ni]);
                    const int slot = mi * 4 + r;
                    if (s < v1[slot]) {               // strict <: lowest k wins
                        v2[slot] = v1[slot];
                        i12[slot] = (k << 16) | (i12[slot] >> 16);
                        v1[slot] = s;
                    } else if (s < v2[slot]) {
                        v2[slot] = s;
                        i12[slot] = (i12[slot] & 0xffff0000) | k;
                    }
                }
        }
    }

    // cross-lane top2 reduce over the 16 lanes sharing each point row,
    // deposit per (point, column-half) into LDS
#pragma unroll
    for (int slot = 0; slot < 16; ++slot) {
        float a1 = v1[slot], a2 = v2[slot];
        int b1 = i12[slot] >> 16, b2 = i12[slot] & 0xffff;
#pragma unroll
        for (int m = 1; m < 16; m <<= 1) {
            const float c1 = __shfl_xor(a1, m, 64);
            const int   d1 = __shfl_xor(b1, m, 64);
            const float c2 = __shfl_xor(a2, m, 64);
            const int   d2 = __shfl_xor(b2, m, 64);
            if (c1 < a1 || (c1 == a1 && d1 < b1)) {
                if (a1 < c2 || (a1 == c2 && b1 < d2)) { a2 = a1; b2 = b1; }
                else { a2 = c2; b2 = d2; }
                a1 = c1; b1 = d1;
            } else {
                if (c1 < a2 || (c1 == a2 && d1 < b2)) { a2 = c1; b2 = d1; }
            }
        }
        if ((l & 15) == 0) {
            const int sm = slot >> 2, sr = slot & 3;
            const int pr = wmb + sm * 16 + (l >> 4) * 4 + sr;  // 0..127
            const int h = w & 1;                               // column half
            mv1[pr][h] = a1; mj1[pr][h] = b1;
            mv2[pr][h] = a2; mj2[pr][h] = b2;
        }
    }
    __syncthreads();
    // merge the two column-halves per point; single global write
    if (tid < 128) {
        float a1 = mv1[tid][0], a2 = mv2[tid][0];
        int b1 = mj1[tid][0], b2 = mj2[tid][0];
        const float c1 = mv1[tid][1], c2 = mv2[tid][1];
        const int   d1 = mj1[tid][1], d2 = mj2[tid][1];
        if (c1 < a1 || (c1 == a1 && d1 < b1)) {
            if (a1 < c2 || (a1 == c2 && b1 < d2)) { a2 = a1; b2 = b1; }
            else { a2 = c2; b2 = d2; }
            a1 = c1; b1 = d1;
        } else {
            if (c1 < a2 || (c1 == a2 && d1 < b2)) { a2 = c1; b2 = d1; }
        }
        const size_t o = (size_t)nsplit * N_PTS + pbase + tid;
        pv1[o] = a1; pi1[o] = b1; pv2[o] = a2; pi2[o] = b2;
    }
}

// ---------------------------------------------------------------- gather
// R17: wave-per-point. Partials merge + rare fp64 rescore (unchanged
// comparator/scan order), then out_q = cb[bi] copy and
// psums[p] = |z_p|^2 (from prep) + s_final. No z_e stream in main path.
__global__ __launch_bounds__(256) void gather_kernel(
    const float* __restrict__ z_e, const float* __restrict__ cb,
    const float* __restrict__ pv1, const int* __restrict__ pi1,
    const float* __restrict__ pv2, const int* __restrict__ pi2,
    float* __restrict__ out_q, float* __restrict__ out_idx,
    unsigned int* __restrict__ counts, float* __restrict__ psums) {
    const int wid  = threadIdx.x >> 6;          // wave 0..3
    const int lane = threadIdx.x & 63;
    const int p    = blockIdx.x * 4 + wid;      // point index

    const float zn = psums[p];                  // |z_p|^2 (written by prep)

    // lane s (s < 16) holds split s's partials
    float lv1 = 3.0e38f, lv2 = 3.0e38f;
    int   li1 = 0x7fffffff, li2 = 0x7fffffff;
    if (lane < NSPLIT) {
        const size_t o = (size_t)lane * N_PTS + p;
        lv1 = pv1[o]; li1 = pi1[o];
        lv2 = pv2[o]; li2 = pi2[o];
    }

    // merge scan (every lane computes the same values via broadcasts)
    float bv = 3.0e38f; int bi = 0x7fffffff;
#pragma unroll
    for (int s = 0; s < NSPLIT; ++s) {
        const float v = __shfl(lv1, s, 64);
        const int   i = __shfl(li1, s, 64);
        if (v < bv || (v == bv && i < bi)) { bv = v; bi = i; }
    }
    float second = 3.0e38f;
    int cand[8]; int nc = 1; cand[0] = bi;
#pragma unroll
    for (int s = 0; s < NSPLIT; ++s) {
        const float v  = __shfl(lv1, s, 64);
        const int   i  = __shfl(li1, s, 64);
        const float w2 = __shfl(lv2, s, 64);
        const int   j  = __shfl(li2, s, 64);
        if (i != bi) {
            if (v < second) second = v;
            if (v <= bv + MARGIN && nc < 8) cand[nc++] = i;
        }
        if (j != bi) {
            if (w2 < second) second = w2;
            if (w2 <= bv + MARGIN && nc < 8) cand[nc++] = j;
        }
    }

    float sfinal = bv;                          // screened |c|^2 - 2<z,c>
    if (second - bv <= MARGIN && nc > 1) {      // wave-uniform condition
        double bestv = 1.0e300; int besti = 0x7fffffff;
        for (int c = 0; c < nc; ++c) {
            const int k = cand[c];
            double part = 0.0;
#pragma unroll
            for (int j = 0; j < 8; ++j) {
                const int d = lane * 8 + j;
                const double cv = (double)cb[(size_t)k * DIM + d];
                const double zv = (double)z_e[(size_t)p * DIM + d];
                part += cv * cv - 2.0 * zv * cv;
            }
#pragma unroll
            for (int o = 32; o > 0; o >>= 1) part += __shfl_down(part, o, 64);
            const double s = __shfl(part, 0, 64);
            if (s < bestv || (s == bestv && k < besti)) { bestv = s; besti = k; }
        }
        bi = besti;
        sfinal = (float)bestv;
    }

    // straight-through output: z + (c - z) == c to 1 ulp (bf16-compare-safe)
    const float4* cp = (const float4*)(cb + (size_t)bi * DIM);
    float4* op = (float4*)(out_q + (size_t)p * DIM);
    op[lane * 2]     = cp[lane * 2];
    op[lane * 2 + 1] = cp[lane * 2 + 1];
    if (lane == 0) {
        psums[p] = zn + sfinal;                 // |z - c|^2
        out_idx[p] = (float)bi;
        atomicAdd(&counts[bi], 1u);
    }
}

// ---------------------------------------------------------------- finalize
__global__ __launch_bounds__(256) void finalize_kernel(
    const unsigned int* __restrict__ counts, const float* __restrict__ psums,
    float* __restrict__ out_scalars) {
    const int t = threadIdx.x;
    float ent = 0.0f;
    for (int b = t; b < K_CODES; b += 256) {
        const float pr = (float)counts[b] * (1.0f / 16384.0f);
        ent += pr * logf(pr + 1e-10f);
    }
    float ss = 0.0f;
    for (int i = t; i < N_PTS; i += 256) ss += psums[i];
#pragma unroll
    for (int off = 32; off > 0; off >>= 1) {
        ent += __shfl_down(ent, off, 64);
        ss += __shfl_down(ss, off, 64);
    }
    __shared__ float re[4], rs[4];
    if ((t & 63) == 0) { re[t >> 6] = ent; rs[t >> 6] = ss; }
    __syncthreads();
    if (t == 0) {
        const float loss = (rs[0] + rs[1] + rs[2] + rs[3]) * (1.0f / NELEM_F);
        out_scalars[0] = loss;
        out_scalars[1] = loss;
        out_scalars[2] = expf(-(re[0] + re[1] + re[2] + re[3]));
    }
}

// ================================================================ fallback
// round-1 pure fp32 path (used only if ws_size < WS_NEED)
#define FB_SPLIT 4
#define FB_KS    (K_CODES / FB_SPLIT)
#define FB_MT    128
#define FB_KT    128
#define FB_DT    32
#define FB_PITCH 36

__global__ __launch_bounds__(256, 2) void fb_dist_argmin_kernel(
    const float* __restrict__ z_e, const float* __restrict__ cb,
    const float* __restrict__ cnorm,
    float* __restrict__ pmin, int* __restrict__ pidx) {
    __shared__ float xs[FB_MT * FB_PITCH];
    __shared__ float cs[FB_KT * FB_PITCH];
    const int tid = threadIdx.x;
    const int tx = tid & 15, ty = tid >> 4;
    const int pbase = blockIdx.x * FB_MT;
    const int kbase0 = blockIdx.y * FB_KS;
    const int scol = (tid & 7) * 4, srow0 = tid >> 3;
    float mn[8], acc[8][8];
    int mi[8];
#pragma unroll
    for (int i = 0; i < 8; ++i) { mn[i] = 3.0e38f; mi[i] = 0; }
    for (int kt = 0; kt < FB_KS / FB_KT; ++kt) {
        const int kbase = kbase0 + kt * FB_KT;
#pragma unroll
        for (int i = 0; i < 8; ++i)
#pragma unroll
            for (int j = 0; j < 8; ++j) acc[i][j] = 0.0f;
        for (int dc = 0; dc < DIM / FB_DT; ++dc) {
            const int dbase = dc * FB_DT;
            __syncthreads();
#pragma unroll
            for (int it = 0; it < 4; ++it) {
                const int row = srow0 + it * 32;
                *(float4*)(xs + row * FB_PITCH + scol) =
                    *(const float4*)(z_e + (size_t)(pbase + row) * DIM + dbase + scol);
                *(float4*)(cs + row * FB_PITCH + scol) =
                    *(const float4*)(cb + (size_t)(kbase + row) * DIM + dbase + scol);
            }
            __syncthreads();
#pragma unroll 2
            for (int dd = 0; dd < FB_DT; dd += 4) {
                float4 xv[8], cv[8];
#pragma unroll
                for (int i = 0; i < 8; ++i)
                    xv[i] = *(const float4*)(xs + (ty + 16 * i) * FB_PITCH + dd);
#pragma unroll
                for (int j = 0; j < 8; ++j)
                    cv[j] = *(const float4*)(cs + (tx + 16 * j) * FB_PITCH + dd);
#pragma unroll
                for (int i = 0; i < 8; ++i)
#pragma unroll
                    for (int j = 0; j < 8; ++j)
                        acc[i][j] += xv[i].x * cv[j].x + xv[i].y * cv[j].y +
                                     xv[i].z * cv[j].z + xv[i].w * cv[j].w;
            }
        }
#pragma unroll
        for (int j = 0; j < 8; ++j) {
            const int k = kbase + tx + 16 * j;
            const float cn = cnorm[k];
#pragma unroll
            for (int i = 0; i < 8; ++i) {
                const float s = cn - 2.0f * acc[i][j];
                if (s < mn[i]) { mn[i] = s; mi[i] = k; }
            }
        }
    }
    float* rmin = xs;
    int* ridx = (int*)cs;
    __syncthreads();
#pragma unroll
    for (int i = 0; i < 8; ++i) {
        const int p = ty + 16 * i;
        rmin[p * 16 + tx] = mn[i];
        ridx[p * 16 + tx] = mi[i];
    }
    __syncthreads();
    if (tid < FB_MT) {
        float best = rmin[tid * 16];
        int bi = ridx[tid * 16];
#pragma unroll
        for (int t = 1; t < 16; ++t) {
            const float v = rmin[tid * 16 + t];
            const int k2 = ridx[tid * 16 + t];
            if (v < best || (v == best && k2 < bi)) { best = v; bi = k2; }
        }
        pmin[(size_t)blockIdx.y * N_PTS + pbase + tid] = best;
        pidx[(size_t)blockIdx.y * N_PTS + pbase + tid] = bi;
    }
}

__global__ __launch_bounds__(128) void fb_gather_kernel(
    const float* __restrict__ z_e, const float* __restrict__ cb,
    const float* __restrict__ pmin, const int* __restrict__ pidx,
    float* __restrict__ out_q, float* __restrict__ out_idx,
    unsigned int* __restrict__ counts, float* __restrict__ psums) {
    const int p = blockIdx.x;
    const int t = threadIdx.x;
    float best = pmin[p];
    int bi = pidx[p];
#pragma unroll
    for (int s = 1; s < FB_SPLIT; ++s) {
        const float v = pmin[(size_t)s * N_PTS + p];
        const int k2 = pidx[(size_t)s * N_PTS + p];
        if (v < best || (v == best && k2 < bi)) { best = v; bi = k2; }
    }
    const float4 z = *(const float4*)(z_e + (size_t)p * DIM + t * 4);
    const float4 c = *(const float4*)(cb + (size_t)bi * DIM + t * 4);
    float4 d, o;
    d.x = c.x - z.x; d.y = c.y - z.y; d.z = c.z - z.z; d.w = c.w - z.w;
    o.x = z.x + d.x; o.y = z.y + d.y; o.z = z.z + d.z; o.w = z.w + d.w;
    *(float4*)(out_q + (size_t)p * DIM + t * 4) = o;
    float ls = d.x * d.x + d.y * d.y + d.z * d.z + d.w * d.w;
#pragma unroll
    for (int off = 32; off > 0; off >>= 1) ls += __shfl_down(ls, off, 64);
    __shared__ float red[2];
    if ((t & 63) == 0) red[t >> 6] = ls;
    __syncthreads();
    if (t == 0) {
        psums[p] = red[0] + red[1];
        out_idx[p] = (float)bi;
        atomicAdd(&counts[bi], 1u);
    }
}

// ================================================================ launch
extern "C" void kernel_launch(void* const* d_in, const int* in_sizes, int n_in,
                              void* d_out, int out_size, void* d_ws, size_t ws_size,
                              hipStream_t stream) {
    const float* z_e = (const float*)d_in[0];
    const float* cb  = (const float*)d_in[1];
    float* out = (float*)d_out;
    char* ws = (char*)d_ws;

    if (ws_size >= WS_NEED) {
        _Float16* A3      = (_Float16*)(ws + OFF_A3);
        _Float16* B3      = (_Float16*)(ws + OFF_B3);
        float* cnorm      = (float*)(ws + OFF_CN);
        float* pv1        = (float*)(ws + OFF_PV1);
        int* pi1          = (int*)(ws + OFF_PI1);
        float* pv2        = (float*)(ws + OFF_PV2);
        int* pi2          = (int*)(ws + OFF_PI2);
        float* psums      = (float*)(ws + OFF_PSUM);
        unsigned int* cnt = (unsigned int*)(ws + OFF_CNT);

        prep_all<<<1024, 256, 0, stream>>>(z_e, cb, A3, B3, cnorm, cnt, psums);
        dim3 g(N_PTS / 128, NSPLIT);                   // 128 x 16 blocks
        score_kernel<<<g, 256, 0, stream>>>(A3, B3, cnorm, pv1, pi1, pv2, pi2);
        gather_kernel<<<N_PTS / 4, 256, 0, stream>>>(z_e, cb, pv1, pi1, pv2, pi2,
                                                     out, out + OUT0_N, cnt, psums);
        finalize_kernel<<<1, 256, 0, stream>>>(cnt, psums, out + OUT0_N + N_PTS);
    } else {
        // round-1 fp32 fallback (<700 KB ws)
        float* cnorm      = (float*)ws;
        float* pmin       = (float*)(ws + 32768);
        int* pidx         = (int*)(ws + 32768 + 262144);
        unsigned int* cnt = (unsigned int*)(ws + 32768 + 2 * 262144);
        float* psums      = (float*)(ws + 32768 + 2 * 262144 + 32768);

        hipMemsetAsync(cnt, 0, 32768, stream);
        cnorm_kernel<<<K_CODES, 128, 0, stream>>>(cb, cnorm);
        dim3 grid1(N_PTS / FB_MT, FB_SPLIT);
        fb_dist_argmin_kernel<<<grid1, 256, 0, stream>>>(z_e, cb, cnorm, pmin, pidx);
        fb_gather_kernel<<<N_PTS, 128, 0, stream>>>(z_e, cb, pmin, pidx,
                                                    out, out + OUT0_N, cnt, psums);
        finalize_kernel<<<1, 256, 0, stream>>>(cnt, psums, out + OUT0_N + N_PTS);
    }
}